// Round 1
// baseline (844.946 us; speedup 1.0000x reference)
//
#include <hip/hip_runtime.h>

namespace {

constexpr int kB = 262144;
constexpr float kScale = 0.44721359549995793f; // 1/sqrt(5)
constexpr float kEps = 1e-5f;

__device__ __forceinline__ void load20(const float* __restrict__ p, float* w) {
    const float4* p4 = reinterpret_cast<const float4*>(p);
#pragma unroll
    for (int i = 0; i < 5; ++i) {
        float4 t = p4[i];
        w[4 * i + 0] = t.x; w[4 * i + 1] = t.y;
        w[4 * i + 2] = t.z; w[4 * i + 3] = t.w;
    }
}

__device__ __forceinline__ float dot20(const float* w, const float* x, float bias) {
    float a0 = bias, a1 = 0.f;
#pragma unroll
    for (int i = 0; i < 20; i += 2) {
        a0 = fmaf(w[i], x[i], a0);
        a1 = fmaf(w[i + 1], x[i + 1], a1);
    }
    return a0 + a1;
}

__device__ __forceinline__ void layernorm20(const float* y, const float* __restrict__ g,
                                            const float* __restrict__ be, float* xout) {
    float s0 = 0.f, s1 = 0.f;
#pragma unroll
    for (int i = 0; i < 20; i += 2) { s0 += y[i]; s1 += y[i + 1]; }
    float m = (s0 + s1) * 0.05f;
    float v0 = 0.f, v1 = 0.f;
#pragma unroll
    for (int i = 0; i < 20; i += 2) {
        float d0 = y[i] - m, d1 = y[i + 1] - m;
        v0 = fmaf(d0, d0, v0);
        v1 = fmaf(d1, d1, v1);
    }
    float r = rsqrtf((v0 + v1) * 0.05f + kEps);
#pragma unroll
    for (int i = 0; i < 20; ++i) xout[i] = fmaf((y[i] - m) * r, g[i], be[i]);
}

__global__ __launch_bounds__(256, 2)
void oat_fused(const float* __restrict__ obs, const float* __restrict__ act,
               const float* __restrict__ W1, const float* __restrict__ b1,
               const float* __restrict__ W2, const float* __restrict__ b2,
               const float* __restrict__ W3, const float* __restrict__ b3,
               const float* __restrict__ Wobs, const float* __restrict__ bobs,
               const float* __restrict__ Wact, const float* __restrict__ bact,
               const float* __restrict__ pos,
               const float* __restrict__ Wqkv, const float* __restrict__ bqkv,
               const float* __restrict__ Wo, const float* __restrict__ bo,
               const float* __restrict__ g1, const float* __restrict__ be1,
               const float* __restrict__ Wf1, const float* __restrict__ bf1,
               const float* __restrict__ Wf2, const float* __restrict__ bf2,
               const float* __restrict__ g2, const float* __restrict__ be2,
               const float* __restrict__ Wfc, const float* __restrict__ bfc,
               float* __restrict__ out) {
    const int b = blockIdx.x * 256 + threadIdx.x;

    // ---- load obs/act ------------------------------------------------------
    float oa[23];
#pragma unroll
    for (int i = 0; i < 17; ++i) oa[i] = obs[b * 17 + i];
#pragma unroll
    for (int i = 0; i < 6; ++i) oa[17 + i] = act[b * 6 + i];

    // ---- MLP layer 1: 23 -> 100 (fully unrolled so h1 stays in VGPRs) -----
    float h1[100];
#pragma unroll
    for (int j = 0; j < 100; ++j) {
        float a0 = b1[j], a1 = 0.f;
#pragma unroll
        for (int k = 0; k < 22; k += 2) {
            a0 = fmaf(W1[j * 23 + k], oa[k], a0);
            a1 = fmaf(W1[j * 23 + k + 1], oa[k + 1], a1);
        }
        a0 = fmaf(W1[j * 23 + 22], oa[22], a0);
        h1[j] = fmaxf(a0 + a1, 0.f);
    }

    // ---- MLP layers 2+3 fused: 100 -> 300 -> 20 (j-loop rolled) -----------
    float mlp[20];
#pragma unroll
    for (int i = 0; i < 20; ++i) mlp[i] = b3[i];
#pragma unroll 1
    for (int j = 0; j < 300; ++j) {
        const float4* w4 = reinterpret_cast<const float4*>(W2 + j * 100);
        float a0 = b2[j], a1 = 0.f, a2 = 0.f, a3 = 0.f;
#pragma unroll
        for (int k = 0; k < 25; ++k) {
            float4 w = w4[k];
            a0 = fmaf(w.x, h1[4 * k + 0], a0);
            a1 = fmaf(w.y, h1[4 * k + 1], a1);
            a2 = fmaf(w.z, h1[4 * k + 2], a2);
            a3 = fmaf(w.w, h1[4 * k + 3], a3);
        }
        float t = fmaxf((a0 + a1) + (a2 + a3), 0.f);
#pragma unroll
        for (int i = 0; i < 20; ++i) mlp[i] = fmaf(W3[i * 300 + j], t, mlp[i]);
    }

    // ---- projections + stack + pos -----------------------------------------
    float x[3][20];
#pragma unroll
    for (int i = 0; i < 20; ++i) x[0][i] = mlp[i] + pos[i];
#pragma unroll
    for (int i = 0; i < 20; ++i) {
        float a0 = bobs[i], a1 = 0.f;
#pragma unroll
        for (int k = 0; k < 16; k += 2) {
            a0 = fmaf(Wobs[i * 17 + k], oa[k], a0);
            a1 = fmaf(Wobs[i * 17 + k + 1], oa[k + 1], a1);
        }
        a0 = fmaf(Wobs[i * 17 + 16], oa[16], a0);
        x[1][i] = a0 + a1 + pos[20 + i];
    }
#pragma unroll
    for (int i = 0; i < 20; ++i) {
        float a0 = bact[i], a1 = 0.f;
#pragma unroll
        for (int k = 0; k < 6; k += 2) {
            a0 = fmaf(Wact[i * 6 + k], oa[17 + k], a0);
            a1 = fmaf(Wact[i * 6 + k + 1], oa[17 + k + 1], a1);
        }
        x[2][i] = a0 + a1 + pos[40 + i];
    }

    // ---- 3 encoder layers (layer loop rolled; weights offset by l) ---------
#pragma unroll 1
    for (int l = 0; l < 3; ++l) {
        const float* Wqkv_l = Wqkv + l * 1200;
        const float* bqkv_l = bqkv + l * 60;
        const float* Wo_l = Wo + l * 400;
        const float* bo_l = bo + l * 20;
        const float* g1_l = g1 + l * 20;
        const float* be1_l = be1 + l * 20;
        const float* Wf1_l = Wf1 + l * 2560;
        const float* bf1_l = bf1 + l * 128;
        const float* Wf2_l = Wf2 + l * 2560;
        const float* bf2_l = bf2 + l * 20;
        const float* g2_l = g2 + l * 20;
        const float* be2_l = be2 + l * 20;

        // ---- attention (H=4 heads, DH=5, S=3) ----
        float o_[3][20];
#pragma unroll
        for (int s = 0; s < 3; ++s)
#pragma unroll
            for (int i = 0; i < 20; ++i) o_[s][i] = 0.f;

#pragma unroll
        for (int h = 0; h < 4; ++h) {
            float q[3][5], k[3][5], v[3][5];
#pragma unroll
            for (int d = 0; d < 5; ++d) {
                float wq[20], wk[20], wv[20];
                load20(Wqkv_l + (h * 5 + d) * 20, wq);
                load20(Wqkv_l + (20 + h * 5 + d) * 20, wk);
                load20(Wqkv_l + (40 + h * 5 + d) * 20, wv);
                const float bq = bqkv_l[h * 5 + d];
                const float bk = bqkv_l[20 + h * 5 + d];
                const float bv = bqkv_l[40 + h * 5 + d];
#pragma unroll
                for (int s = 0; s < 3; ++s) {
                    q[s][d] = dot20(wq, x[s], bq);
                    k[s][d] = dot20(wk, x[s], bk);
                    v[s][d] = dot20(wv, x[s], bv);
                }
            }
#pragma unroll
            for (int s = 0; s < 3; ++s) {
                float sc[3];
#pragma unroll
                for (int t = 0; t < 3; ++t) {
                    float a = 0.f;
#pragma unroll
                    for (int d = 0; d < 5; ++d) a = fmaf(q[s][d], k[t][d], a);
                    sc[t] = a * kScale;
                }
                float m = fmaxf(sc[0], fmaxf(sc[1], sc[2]));
                float e0 = __expf(sc[0] - m), e1 = __expf(sc[1] - m), e2 = __expf(sc[2] - m);
                float inv = 1.f / (e0 + e1 + e2);
                e0 *= inv; e1 *= inv; e2 *= inv;
#pragma unroll
                for (int d = 0; d < 5; ++d)
                    o_[s][h * 5 + d] = fmaf(e0, v[0][d], fmaf(e1, v[1][d], e2 * v[2][d]));
            }
        }

        // ---- Wo + residual + LN1 ----
        float y[3][20];
#pragma unroll
        for (int i = 0; i < 20; ++i) {
            float w[20];
            load20(Wo_l + i * 20, w);
            const float bb = bo_l[i];
#pragma unroll
            for (int s = 0; s < 3; ++s) y[s][i] = x[s][i] + dot20(w, o_[s], bb);
        }
#pragma unroll
        for (int s = 0; s < 3; ++s) layernorm20(y[s], g1_l, be1_l, x[s]);

        // ---- FFN 20 -> 128 -> 20 (j-loop rolled) ----
        float ff[3][20];
#pragma unroll
        for (int s = 0; s < 3; ++s)
#pragma unroll
            for (int i = 0; i < 20; ++i) ff[s][i] = bf2_l[i];
#pragma unroll 1
        for (int j = 0; j < 128; ++j) {
            float w[20];
            load20(Wf1_l + j * 20, w);
            const float bb = bf1_l[j];
            float t0 = fmaxf(dot20(w, x[0], bb), 0.f);
            float t1 = fmaxf(dot20(w, x[1], bb), 0.f);
            float t2 = fmaxf(dot20(w, x[2], bb), 0.f);
#pragma unroll
            for (int i = 0; i < 20; ++i) {
                const float wo = Wf2_l[i * 128 + j];
                ff[0][i] = fmaf(wo, t0, ff[0][i]);
                ff[1][i] = fmaf(wo, t1, ff[1][i]);
                ff[2][i] = fmaf(wo, t2, ff[2][i]);
            }
        }
#pragma unroll
        for (int s = 0; s < 3; ++s) {
            float y2[20];
#pragma unroll
            for (int i = 0; i < 20; ++i) y2[i] = x[s][i] + ff[s][i];
            layernorm20(y2, g2_l, be2_l, x[s]);
        }
    }

    // ---- final head: (B,60) @ Wfc.T + bfc ----------------------------------
    float a0 = bfc[0], a1 = 0.f;
#pragma unroll
    for (int s = 0; s < 3; ++s)
#pragma unroll
        for (int i = 0; i < 20; i += 2) {
            a0 = fmaf(x[s][i], Wfc[s * 20 + i], a0);
            a1 = fmaf(x[s][i + 1], Wfc[s * 20 + i + 1], a1);
        }
    out[b] = a0 + a1;
}

} // namespace

extern "C" void kernel_launch(void* const* d_in, const int* in_sizes, int n_in,
                              void* d_out, int out_size, void* d_ws, size_t ws_size,
                              hipStream_t stream) {
    (void)in_sizes; (void)n_in; (void)d_ws; (void)ws_size; (void)out_size;
    const float* obs  = (const float*)d_in[0];
    const float* act  = (const float*)d_in[1];
    const float* W1   = (const float*)d_in[2];
    const float* b1   = (const float*)d_in[3];
    const float* W2   = (const float*)d_in[4];
    const float* b2   = (const float*)d_in[5];
    const float* W3   = (const float*)d_in[6];
    const float* b3   = (const float*)d_in[7];
    const float* Wobs = (const float*)d_in[8];
    const float* bobs = (const float*)d_in[9];
    const float* Wact = (const float*)d_in[10];
    const float* bact = (const float*)d_in[11];
    const float* pos  = (const float*)d_in[12];
    const float* Wqkv = (const float*)d_in[13];
    const float* bqkv = (const float*)d_in[14];
    const float* Wo   = (const float*)d_in[15];
    const float* bo   = (const float*)d_in[16];
    const float* g1   = (const float*)d_in[17];
    const float* be1  = (const float*)d_in[18];
    const float* Wf1  = (const float*)d_in[19];
    const float* bf1  = (const float*)d_in[20];
    const float* Wf2  = (const float*)d_in[21];
    const float* bf2  = (const float*)d_in[22];
    const float* g2   = (const float*)d_in[23];
    const float* be2  = (const float*)d_in[24];
    const float* Wfc  = (const float*)d_in[25];
    const float* bfc  = (const float*)d_in[26];

    dim3 grid(kB / 256), block(256);
    hipLaunchKernelGGL(oat_fused, grid, block, 0, stream,
                       obs, act, W1, b1, W2, b2, W3, b3, Wobs, bobs, Wact, bact,
                       pos, Wqkv, bqkv, Wo, bo, g1, be1, Wf1, bf1, Wf2, bf2,
                       g2, be2, Wfc, bfc, (float*)d_out);
}

// Round 2
// 392.793 us; speedup vs baseline: 2.1511x; 2.1511x over previous
//
#include <hip/hip_runtime.h>

typedef unsigned short ushort_t;
typedef short bf16x8 __attribute__((ext_vector_type(8)));
typedef float f32x4 __attribute__((ext_vector_type(4)));

#define MFMA16(a, b, c) __builtin_amdgcn_mfma_f32_16x16x32_bf16((a), (b), (c), 0, 0, 0)

namespace {

constexpr int kB = 262144;

// ws B-fragment set bases (1 set = 64 lanes x 8 bf16 = 512 elems = 1 KiB)
constexpr int SET_W1 = 0;     // (100,23)  NT=7  KS=1
constexpr int SET_W2 = 7;     // (300,100) NT=20 KS=4
constexpr int SET_W3 = 87;    // (20,300)  NT=2  KS=10
constexpr int SET_WOBS = 107; // (20,17)   NT=2  KS=1
constexpr int SET_WACT = 109; // (20,6)    NT=2  KS=1, k shifted +17
constexpr int SET_WQKV = 111; // 3 x (60,20)  NT=4 KS=1
constexpr int SET_WO = 123;   // 3 x (20,20)  NT=2 KS=1
constexpr int SET_WF1 = 129;  // 3 x (128,20) NT=8 KS=1
constexpr int SET_WF2 = 153;  // 3 x (20,128) NT=2 KS=4
constexpr int NSETS = 177;    // total ws = 177 KiB

// LDS per-wave arena offsets (ushort units). Total 8192 (16 KiB/wave).
constexpr int L_ACT = 0;    // [16][136]  h1 / ffn hidden (pitch 136 -> 272B rows, 2-way-free banks)
constexpr int L_H2T = 2176; // [16][40]   h2 pair-tile staging
constexpr int L_XA = 2816;  // [3][16][40] x as A-operand (also oa staging in token0)
constexpr int L_QKV = 4736; // [3][16][72] qkv (q:0-19 k:20-39 v:40-59), o overwrites q

__device__ __forceinline__ ushort_t f2bf(float f) {
    unsigned u = __float_as_uint(f);
    return (ushort_t)((u + 0x7FFFu + ((u >> 16) & 1u)) >> 16);
}
__device__ __forceinline__ float bf2f(ushort_t h) {
    return __uint_as_float(((unsigned)h) << 16);
}

// ---------------- weight prep: fp32 -> bf16 B-fragments in ws ---------------
__global__ void prep_weights(const float* __restrict__ W1, const float* __restrict__ W2,
                             const float* __restrict__ W3, const float* __restrict__ Wobs,
                             const float* __restrict__ Wact, const float* __restrict__ Wqkv,
                             const float* __restrict__ Wo, const float* __restrict__ Wf1,
                             const float* __restrict__ Wf2, ushort_t* __restrict__ ws) {
    int s = blockIdx.x, lane = threadIdx.x;
    const float* src;
    int Nout, Kin, kshift = 0, nt, ks;
    if (s < SET_W2) { src = W1; Nout = 100; Kin = 23; nt = s; ks = 0; }
    else if (s < SET_W3) { int t = s - SET_W2; src = W2; Nout = 300; Kin = 100; nt = t >> 2; ks = t & 3; }
    else if (s < SET_WOBS) { int t = s - SET_W3; src = W3; Nout = 20; Kin = 300; nt = t / 10; ks = t % 10; }
    else if (s < SET_WACT) { int t = s - SET_WOBS; src = Wobs; Nout = 20; Kin = 17; nt = t; ks = 0; }
    else if (s < SET_WQKV) { int t = s - SET_WACT; src = Wact; Nout = 20; Kin = 6; kshift = 17; nt = t; ks = 0; }
    else if (s < SET_WO) { int t = s - SET_WQKV; src = Wqkv + (t >> 2) * 1200; Nout = 60; Kin = 20; nt = t & 3; ks = 0; }
    else if (s < SET_WF1) { int t = s - SET_WO; src = Wo + (t >> 1) * 400; Nout = 20; Kin = 20; nt = t & 1; ks = 0; }
    else if (s < SET_WF2) { int t = s - SET_WF1; src = Wf1 + (t >> 3) * 2560; Nout = 128; Kin = 20; nt = t & 7; ks = 0; }
    else { int t = s - SET_WF2; src = Wf2 + (t >> 3) * 2560; Nout = 20; Kin = 128; int r = t & 7; nt = r >> 2; ks = r & 3; }

    int n = nt * 16 + (lane & 15);
    int k0 = ks * 32 + (lane >> 4) * 8;
    ushort_t h[8];
#pragma unroll
    for (int j = 0; j < 8; ++j) {
        int k = k0 + j;
        float v = 0.f;
        if (n < Nout && k >= kshift && k < kshift + Kin) v = src[n * Kin + (k - kshift)];
        h[j] = f2bf(v);
    }
    uint4 pk;
    pk.x = (unsigned)h[0] | ((unsigned)h[1] << 16);
    pk.y = (unsigned)h[2] | ((unsigned)h[3] << 16);
    pk.z = (unsigned)h[4] | ((unsigned)h[5] << 16);
    pk.w = (unsigned)h[6] | ((unsigned)h[7] << 16);
    ((uint4*)ws)[s * 64 + lane] = pk;
}

// LN over 20 cols held in a C-frag pair (cols >=20 are exact zeros on input/output)
__device__ __forceinline__ void ln20(f32x4& y0, f32x4& y1, const float* __restrict__ g,
                                     const float* __restrict__ be, int r16) {
    f32x4 s = y0 + y1;
    f32x4 s2 = y0 * y0 + y1 * y1;
#pragma unroll
    for (int m = 1; m < 16; m <<= 1) {
#pragma unroll
        for (int j = 0; j < 4; ++j) {
            s[j] += __shfl_xor(s[j], m);
            s2[j] += __shfl_xor(s2[j], m);
        }
    }
    float g0 = g[r16], be0 = be[r16];
    float g1v = (r16 < 4) ? g[16 + r16] : 0.f;
    float be1v = (r16 < 4) ? be[16 + r16] : 0.f;
#pragma unroll
    for (int j = 0; j < 4; ++j) {
        float mean = s[j] * 0.05f;
        float var = s2[j] * 0.05f - mean * mean;
        float r = rsqrtf(var + 1e-5f);
        y0[j] = (y0[j] - mean) * r * g0 + be0;
        y1[j] = (y1[j] - mean) * r * g1v + be1v;
    }
}

__device__ __forceinline__ void store_x(ushort_t* S, int t, int kb, int r16,
                                        const f32x4& x0, const f32x4& x1) {
#pragma unroll
    for (int j = 0; j < 4; ++j) {
        S[L_XA + t * 640 + (kb * 4 + j) * 40 + r16] = f2bf(x0[j]);
        S[L_XA + t * 640 + (kb * 4 + j) * 40 + 16 + r16] = f2bf(x1[j]);
    }
}

__global__ __launch_bounds__(128, 2)
void oat_mfma(const float* __restrict__ obs, const float* __restrict__ act,
              const float* __restrict__ b1, const float* __restrict__ b2,
              const float* __restrict__ b3, const float* __restrict__ bobs,
              const float* __restrict__ bact, const float* __restrict__ pos,
              const float* __restrict__ bqkv, const float* __restrict__ bo,
              const float* __restrict__ g1, const float* __restrict__ be1,
              const float* __restrict__ bf1, const float* __restrict__ bf2,
              const float* __restrict__ g2, const float* __restrict__ be2,
              const float* __restrict__ Wfc, const float* __restrict__ bfc,
              const ushort_t* __restrict__ wsb, float* __restrict__ out) {
    __shared__ __align__(16) ushort_t smem[2][8192];
    const int lane = threadIdx.x & 63, wid = threadIdx.x >> 6;
    const int r16 = lane & 15, kb = lane >> 4;
    const int row0 = (blockIdx.x * 2 + wid) * 16;
    ushort_t* S = smem[wid];
    const bf16x8* Bw = (const bf16x8*)wsb;
    const f32x4 zero = {0.f, 0.f, 0.f, 0.f};

    // ---- P0: stage oa (obs|act, K=23 pad 32) into XA token0, bf16 ----------
#pragma unroll
    for (int it = 0; it < 8; ++it) {
        int idx = it * 64 + lane;
        int r = idx >> 5, c = idx & 31;
        float v = 0.f;
        if (c < 17) v = obs[(row0 + r) * 17 + c];
        else if (c < 23) v = act[(row0 + r) * 6 + (c - 17)];
        S[L_XA + r * 40 + c] = f2bf(v);
    }

    // ---- P1: W1 (h1) + projections, all from the same oa A-frag ------------
    bf16x8 aOA = *(const bf16x8*)(S + L_XA + r16 * 40 + kb * 8);
    f32x4 c1[7];
#pragma unroll
    for (int nt = 0; nt < 7; ++nt) c1[nt] = MFMA16(aOA, Bw[(SET_W1 + nt) * 64 + lane], zero);
    f32x4 cPO[2], cPA[2];
#pragma unroll
    for (int nt = 0; nt < 2; ++nt) {
        cPO[nt] = MFMA16(aOA, Bw[(SET_WOBS + nt) * 64 + lane], zero);
        cPA[nt] = MFMA16(aOA, Bw[(SET_WACT + nt) * 64 + lane], zero);
    }
#pragma unroll
    for (int nt = 0; nt < 7; ++nt) {
        int col = nt * 16 + r16;
        float bias = (col < 100) ? b1[col] : 0.f;
#pragma unroll
        for (int j = 0; j < 4; ++j)
            S[L_ACT + (kb * 4 + j) * 136 + col] = f2bf(fmaxf(c1[nt][j] + bias, 0.f));
    }
    // zero cols 112..127 so the ks=3 A-frag never reads uninitialized LDS
#pragma unroll
    for (int j = 0; j < 4; ++j) S[L_ACT + (kb * 4 + j) * 136 + 112 + r16] = 0;

    // ---- P2: W2 -> relu -> (pair-tiles) -> W3, mlp stays in regs -----------
    bf16x8 aH1[4];
#pragma unroll
    for (int ks = 0; ks < 4; ++ks)
        aH1[ks] = *(const bf16x8*)(S + L_ACT + r16 * 136 + kb * 8 + ks * 32);
    f32x4 mout[2];
    mout[0] = zero; mout[1] = zero;
#pragma unroll 1
    for (int np = 0; np < 10; ++np) {
#pragma unroll
        for (int sub = 0; sub < 2; ++sub) {
            int nt = np * 2 + sub;
            f32x4 c = zero;
#pragma unroll
            for (int ks = 0; ks < 4; ++ks)
                c = MFMA16(aH1[ks], Bw[(SET_W2 + nt * 4 + ks) * 64 + lane], c);
            int col = nt * 16 + r16;
            float bias = (col < 300) ? b2[col] : 0.f;
#pragma unroll
            for (int j = 0; j < 4; ++j)
                S[L_H2T + (kb * 4 + j) * 40 + sub * 16 + r16] = f2bf(fmaxf(c[j] + bias, 0.f));
        }
        bf16x8 aH2 = *(const bf16x8*)(S + L_H2T + r16 * 40 + kb * 8);
#pragma unroll
        for (int nt2 = 0; nt2 < 2; ++nt2)
            mout[nt2] = MFMA16(aH2, Bw[(SET_W3 + nt2 * 10 + np) * 64 + lane], mout[nt2]);
    }

    // ---- P3: stack + pos -> xf C-frags; write xA ---------------------------
    f32x4 xf[3][2];
#pragma unroll
    for (int nt = 0; nt < 2; ++nt) {
        int col = nt * 16 + r16;
        bool v = col < 20;
        float a0 = v ? (b3[col] + pos[col]) : 0.f;
        float a1 = v ? (bobs[col] + pos[20 + col]) : 0.f;
        float a2 = v ? (bact[col] + pos[40 + col]) : 0.f;
        xf[0][nt] = mout[nt];
        xf[1][nt] = cPO[nt];
        xf[2][nt] = cPA[nt];
#pragma unroll
        for (int j = 0; j < 4; ++j) {
            xf[0][nt][j] += a0;
            xf[1][nt][j] += a1;
            xf[2][nt][j] += a2;
        }
    }
#pragma unroll
    for (int t = 0; t < 3; ++t) store_x(S, t, kb, r16, xf[t][0], xf[t][1]);

    // ---- P4: 3 encoder layers ----------------------------------------------
#pragma unroll 1
    for (int l = 0; l < 3; ++l) {
        // QKV GEMM -> qkvA (bf16)
#pragma unroll
        for (int t = 0; t < 3; ++t) {
            bf16x8 aX = *(const bf16x8*)(S + L_XA + t * 640 + r16 * 40 + kb * 8);
#pragma unroll
            for (int nt = 0; nt < 4; ++nt) {
                f32x4 c = MFMA16(aX, Bw[(SET_WQKV + l * 4 + nt) * 64 + lane], zero);
                int col = nt * 16 + r16;
                float bias = (col < 60) ? bqkv[l * 60 + col] : 0.f;
#pragma unroll
                for (int j = 0; j < 4; ++j)
                    S[L_QKV + t * 1152 + (kb * 4 + j) * 72 + col] = f2bf(c[j] + bias);
            }
        }
        // attention: lane = (row, head)
        {
            int ar = lane >> 2, ah = lane & 3;
            const int qb = L_QKV + ar * 72 + ah * 5;
            float q[3][5], kk[3][5], vv[3][5];
#pragma unroll
            for (int s = 0; s < 3; ++s)
#pragma unroll
                for (int d = 0; d < 5; ++d) {
                    q[s][d] = bf2f(S[qb + s * 1152 + d]);
                    kk[s][d] = bf2f(S[qb + s * 1152 + 20 + d]);
                    vv[s][d] = bf2f(S[qb + s * 1152 + 40 + d]);
                }
            float o[3][5];
#pragma unroll
            for (int s = 0; s < 3; ++s) {
                float sc[3];
#pragma unroll
                for (int t2 = 0; t2 < 3; ++t2) {
                    float a = 0.f;
#pragma unroll
                    for (int d = 0; d < 5; ++d) a = fmaf(q[s][d], kk[t2][d], a);
                    sc[t2] = a * 0.44721359549995793f;
                }
                float m = fmaxf(sc[0], fmaxf(sc[1], sc[2]));
                float e0 = __expf(sc[0] - m), e1 = __expf(sc[1] - m), e2 = __expf(sc[2] - m);
                float inv = 1.f / (e0 + e1 + e2);
                e0 *= inv; e1 *= inv; e2 *= inv;
#pragma unroll
                for (int d = 0; d < 5; ++d)
                    o[s][d] = fmaf(e0, vv[0][d], fmaf(e1, vv[1][d], e2 * vv[2][d]));
            }
#pragma unroll
            for (int s = 0; s < 3; ++s)
#pragma unroll
                for (int d = 0; d < 5; ++d)
                    S[qb + s * 1152 + d] = f2bf(o[s][d]);  // o overwrites own q slice
        }
        // per token: Wo + residual + LN1, then FFN + residual + LN2
#pragma unroll
        for (int t = 0; t < 3; ++t) {
            bf16x8 aO = *(const bf16x8*)(S + L_QKV + t * 1152 + r16 * 72 + kb * 8);
            f32x4 cw0 = MFMA16(aO, Bw[(SET_WO + l * 2 + 0) * 64 + lane], zero);
            f32x4 cw1 = MFMA16(aO, Bw[(SET_WO + l * 2 + 1) * 64 + lane], zero);
            float ob0 = bo[l * 20 + r16];
            float ob1 = (r16 < 4) ? bo[l * 20 + 16 + r16] : 0.f;
            f32x4 y0 = xf[t][0], y1 = xf[t][1];
#pragma unroll
            for (int j = 0; j < 4; ++j) { y0[j] += cw0[j] + ob0; y1[j] += cw1[j] + ob1; }
            ln20(y0, y1, g1 + l * 20, be1 + l * 20, r16);
            xf[t][0] = y0; xf[t][1] = y1;
            store_x(S, t, kb, r16, y0, y1);

            // FFN1: x -> 128, relu, into ACT
            bf16x8 aXt = *(const bf16x8*)(S + L_XA + t * 640 + r16 * 40 + kb * 8);
#pragma unroll
            for (int nt = 0; nt < 8; ++nt) {
                f32x4 cf = MFMA16(aXt, Bw[(SET_WF1 + l * 8 + nt) * 64 + lane], zero);
                int col = nt * 16 + r16;
                float bias = bf1[l * 128 + col];
#pragma unroll
                for (int j = 0; j < 4; ++j)
                    S[L_ACT + (kb * 4 + j) * 136 + col] = f2bf(fmaxf(cf[j] + bias, 0.f));
            }
            // FFN2: 128 -> 20
            f32x4 c20 = zero, c21 = zero;
#pragma unroll
            for (int ks = 0; ks < 4; ++ks) {
                bf16x8 aF = *(const bf16x8*)(S + L_ACT + r16 * 136 + kb * 8 + ks * 32);
                c20 = MFMA16(aF, Bw[(SET_WF2 + l * 8 + ks) * 64 + lane], c20);
                c21 = MFMA16(aF, Bw[(SET_WF2 + l * 8 + 4 + ks) * 64 + lane], c21);
            }
            float fb0 = bf2[l * 20 + r16];
            float fb1 = (r16 < 4) ? bf2[l * 20 + 16 + r16] : 0.f;
            f32x4 z0 = xf[t][0], z1 = xf[t][1];
#pragma unroll
            for (int j = 0; j < 4; ++j) { z0[j] += c20[j] + fb0; z1[j] += c21[j] + fb1; }
            ln20(z0, z1, g2 + l * 20, be2 + l * 20, r16);
            xf[t][0] = z0; xf[t][1] = z1;
            store_x(S, t, kb, r16, z0, z1);
        }
    }

    // ---- P5: head (B,60) @ Wfc^T + bfc -------------------------------------
    f32x4 p = zero;
#pragma unroll
    for (int t = 0; t < 3; ++t) {
        float w0 = Wfc[t * 20 + r16];
        float w1 = (r16 < 4) ? Wfc[t * 20 + 16 + r16] : 0.f;
#pragma unroll
        for (int j = 0; j < 4; ++j)
            p[j] = fmaf(xf[t][0][j], w0, fmaf(xf[t][1][j], w1, p[j]));
    }
#pragma unroll
    for (int m = 1; m < 16; m <<= 1)
#pragma unroll
        for (int j = 0; j < 4; ++j) p[j] += __shfl_xor(p[j], m);
    if (r16 < 4) {
        float v = (r16 == 0) ? p[0] : (r16 == 1) ? p[1] : (r16 == 2) ? p[2] : p[3];
        out[row0 + kb * 4 + r16] = v + bfc[0];
    }
}

} // namespace

extern "C" void kernel_launch(void* const* d_in, const int* in_sizes, int n_in,
                              void* d_out, int out_size, void* d_ws, size_t ws_size,
                              hipStream_t stream) {
    (void)in_sizes; (void)n_in; (void)out_size; (void)ws_size;
    const float* obs  = (const float*)d_in[0];
    const float* act  = (const float*)d_in[1];
    const float* W1   = (const float*)d_in[2];
    const float* b1   = (const float*)d_in[3];
    const float* W2   = (const float*)d_in[4];
    const float* b2   = (const float*)d_in[5];
    const float* W3   = (const float*)d_in[6];
    const float* b3   = (const float*)d_in[7];
    const float* Wobs = (const float*)d_in[8];
    const float* bobs = (const float*)d_in[9];
    const float* Wact = (const float*)d_in[10];
    const float* bact = (const float*)d_in[11];
    const float* pos  = (const float*)d_in[12];
    const float* Wqkv = (const float*)d_in[13];
    const float* bqkv = (const float*)d_in[14];
    const float* Wo   = (const float*)d_in[15];
    const float* bo   = (const float*)d_in[16];
    const float* g1   = (const float*)d_in[17];
    const float* be1  = (const float*)d_in[18];
    const float* Wf1  = (const float*)d_in[19];
    const float* bf1  = (const float*)d_in[20];
    const float* Wf2  = (const float*)d_in[21];
    const float* bf2  = (const float*)d_in[22];
    const float* g2   = (const float*)d_in[23];
    const float* be2  = (const float*)d_in[24];
    const float* Wfc  = (const float*)d_in[25];
    const float* bfc  = (const float*)d_in[26];

    ushort_t* wsb = (ushort_t*)d_ws;

    hipLaunchKernelGGL(prep_weights, dim3(NSETS), dim3(64), 0, stream,
                       W1, W2, W3, Wobs, Wact, Wqkv, Wo, Wf1, Wf2, wsb);
    hipLaunchKernelGGL(oat_mfma, dim3(kB / 32), dim3(128), 0, stream,
                       obs, act, b1, b2, b3, bobs, bact, pos, bqkv, bo,
                       g1, be1, bf1, bf2, g2, be2, Wfc, bfc, wsb, (float*)d_out);
}

// Round 3
// 298.724 us; speedup vs baseline: 2.8285x; 1.3149x over previous
//
#include <hip/hip_runtime.h>

typedef unsigned short ushort_t;
typedef short bf16x8 __attribute__((ext_vector_type(8)));
typedef float f32x4 __attribute__((ext_vector_type(4)));

#define MFMA16(a, b, c) __builtin_amdgcn_mfma_f32_16x16x32_bf16((a), (b), (c), 0, 0, 0)

namespace {

constexpr int kB = 262144;

// ws B-fragment set bases (1 set = 64 lanes x 8 bf16 = 1 KiB)
constexpr int SET_W1 = 0;     // (100,23)  NT=7  KS=1
constexpr int SET_W2 = 7;     // (300,100) NT=20 KS=4
constexpr int SET_W3 = 87;    // (20,300)  NT=2  KS=10
constexpr int SET_WOBS = 107; // (20,17)   NT=2  KS=1
constexpr int SET_WACT = 109; // (20,6)    NT=2  KS=1, k shifted +17
constexpr int SET_WQKV = 111; // 3 x (60,20)  NT=4 KS=1
constexpr int SET_WO = 123;   // 3 x (20,20)  NT=2 KS=1
constexpr int SET_WF1 = 129;  // 3 x (128,20) NT=8 KS=1
constexpr int SET_WF2 = 153;  // 3 x (20,128) NT=2 KS=4
constexpr int NSETS = 177;

// per-M-tile LDS arena (ushort units). Arena = 4992 ushorts (9984 B).
constexpr int AR = 4992;
// XA:  [3 tok][16 rows][pitch 40]  x (pair-permuted bf16); token0 doubles as oa staging
// QKV: [3 tok][16 rows][pitch 64]  qkv, dword-XOR-swizzled; o overwrites in place
// ACT: [16][pitch 136]             h1 / ffn hidden — ALIASES QKV (disjoint in time)
// H2T: [16][pitch 40]              W2->W3 staging
constexpr int XAu = 0;     // dword base 0,   row 20 dw, tok 320 dw
constexpr int QKVu = 1920; // dword base 960, row 32 dw, tok 512 dw
constexpr int ACTu = 1920; // dword base 960, row 68 dw
constexpr int H2Tu = 4096; // dword base 2048, row 20 dw

__device__ __forceinline__ unsigned pk_bf16(float lo, float hi) {
    unsigned r;
    asm("v_cvt_pk_bf16_f32 %0, %1, %2" : "=v"(r) : "v"(lo), "v"(hi));
    return r;
}
__device__ __forceinline__ float bf2f(ushort_t h) {
    return __uint_as_float(((unsigned)h) << 16);
}
// feature f (0..63) -> ushort slot in a pair-permuted 64-wide row (no swizzle)
__device__ __forceinline__ int fslot(int f) {
    return ((f >> 5) << 5) + ((f & 15) << 1) + ((f >> 4) & 1);
}
// swizzled ushort offset within a QKV row; sw = (row&7)<<2
__device__ __forceinline__ int qoff(int f, int sw) {
    int s = fslot(f);
    return (((s >> 1) ^ sw) << 1) | (s & 1);
}

// ---------------- weight prep: fp32 -> bf16 B-fragments (permuted k) --------
__global__ void prep_weights(const float* __restrict__ W1, const float* __restrict__ W2,
                             const float* __restrict__ W3, const float* __restrict__ Wobs,
                             const float* __restrict__ Wact, const float* __restrict__ Wqkv,
                             const float* __restrict__ Wo, const float* __restrict__ Wf1,
                             const float* __restrict__ Wf2, ushort_t* __restrict__ ws) {
    int s = blockIdx.x, lane = threadIdx.x;
    const float* src;
    int Nout, Kin, kshift = 0, nt, ks;
    if (s < SET_W2) { src = W1; Nout = 100; Kin = 23; nt = s; ks = 0; }
    else if (s < SET_W3) { int t = s - SET_W2; src = W2; Nout = 300; Kin = 100; nt = t >> 2; ks = t & 3; }
    else if (s < SET_WOBS) { int t = s - SET_W3; src = W3; Nout = 20; Kin = 300; nt = t / 10; ks = t % 10; }
    else if (s < SET_WACT) { int t = s - SET_WOBS; src = Wobs; Nout = 20; Kin = 17; nt = t; ks = 0; }
    else if (s < SET_WQKV) { int t = s - SET_WACT; src = Wact; Nout = 20; Kin = 6; kshift = 17; nt = t; ks = 0; }
    else if (s < SET_WO) { int t = s - SET_WQKV; src = Wqkv + (t >> 2) * 1200; Nout = 60; Kin = 20; nt = t & 3; ks = 0; }
    else if (s < SET_WF1) { int t = s - SET_WO; src = Wo + (t >> 1) * 400; Nout = 20; Kin = 20; nt = t & 1; ks = 0; }
    else if (s < SET_WF2) { int t = s - SET_WF1; src = Wf1 + (t >> 3) * 2560; Nout = 128; Kin = 20; nt = t & 7; ks = 0; }
    else { int t = s - SET_WF2; src = Wf2 + (t >> 3) * 2560; Nout = 20; Kin = 128; int r = t & 7; nt = r >> 2; ks = r & 3; }

    int n = nt * 16 + (lane & 15);
    ushort_t h[8];
#pragma unroll
    for (int j = 0; j < 8; ++j) {
        int m = (lane >> 4) * 8 + j;             // k-slot within 32-span
        int kw = (m >> 1) + ((m & 1) << 4);      // pair-permuted feature within span
        int k = ks * 32 + kw;
        float v = 0.f;
        if (n < Nout && k >= kshift && k < kshift + Kin) v = src[n * Kin + (k - kshift)];
        unsigned u = __float_as_uint(v);
        h[j] = (ushort_t)((u + 0x7FFFu + ((u >> 16) & 1u)) >> 16);
    }
    uint4 pk;
    pk.x = (unsigned)h[0] | ((unsigned)h[1] << 16);
    pk.y = (unsigned)h[2] | ((unsigned)h[3] << 16);
    pk.z = (unsigned)h[4] | ((unsigned)h[5] << 16);
    pk.w = (unsigned)h[6] | ((unsigned)h[7] << 16);
    ((uint4*)ws)[s * 64 + lane] = pk;
}

// LN over 20 valid cols; y1 cols (16+r16)>=20 are exact zeros; ga1/ba1 pre-masked
__device__ __forceinline__ void ln20(f32x4& y0, f32x4& y1, float ga0, float ba0,
                                     float ga1, float ba1) {
    f32x4 s = y0 + y1;
    f32x4 s2 = y0 * y0 + y1 * y1;
#pragma unroll
    for (int m = 1; m < 16; m <<= 1) {
#pragma unroll
        for (int j = 0; j < 4; ++j) {
            s[j] += __shfl_xor(s[j], m);
            s2[j] += __shfl_xor(s2[j], m);
        }
    }
#pragma unroll
    for (int j = 0; j < 4; ++j) {
        float mean = s[j] * 0.05f;
        float var = s2[j] * 0.05f - mean * mean;
        float r = rsqrtf(var + 1e-5f);
        y0[j] = (y0[j] - mean) * r * ga0 + ba0;
        y1[j] = (y1[j] - mean) * r * ga1 + ba1;
    }
}

__global__ __launch_bounds__(64, 2)
void oat_mfma2(const float* __restrict__ obs, const float* __restrict__ act,
               const float* __restrict__ b1, const float* __restrict__ b2,
               const float* __restrict__ b3, const float* __restrict__ bobs,
               const float* __restrict__ bact, const float* __restrict__ pos,
               const float* __restrict__ bqkv, const float* __restrict__ bo,
               const float* __restrict__ g1, const float* __restrict__ be1,
               const float* __restrict__ bf1, const float* __restrict__ bf2,
               const float* __restrict__ g2, const float* __restrict__ be2,
               const float* __restrict__ Wfc, const float* __restrict__ bfc,
               const ushort_t* __restrict__ wsb, float* __restrict__ out) {
    __shared__ __align__(16) ushort_t sm[2 * AR];
    unsigned* smw = (unsigned*)sm;
    const int lane = threadIdx.x;
    const int r16 = lane & 15, kb = lane >> 4;
    const int row0 = blockIdx.x * 32;
    const bf16x8* Bw = (const bf16x8*)wsb;
    const f32x4 zero = {0.f, 0.f, 0.f, 0.f};

    // ---- P0: stage oa (32 features: obs 0..16, act 17..22, pad) ------------
#pragma unroll
    for (int it = 0; it < 8; ++it) {
        int idx = it * 64 + lane;
        int r32 = idx >> 4, d = idx & 15;
        int mt = r32 >> 4, r = r32 & 15;
        int gr = row0 + r32;
        float lo = obs[gr * 17 + d];
        float hi = (d == 0) ? obs[gr * 17 + 16] : ((d <= 6) ? act[gr * 6 + (d - 1)] : 0.f);
        smw[mt * (AR / 2) + r * 20 + d] = pk_bf16(lo, hi);
    }

    // ---- P1: W1 (h1) + obs/act projections, per M-tile ----------------------
    f32x4 xf[3][2][2]; // [token][nt][mt]
    bf16x8 aH1[2][4];
#pragma unroll
    for (int mt = 0; mt < 2; ++mt) {
        const ushort_t* S = sm + mt * AR;
        unsigned* SW = smw + mt * (AR / 2);
        bf16x8 aOA = *(const bf16x8*)(S + r16 * 40 + kb * 8);
        f32x4 c1[7];
#pragma unroll
        for (int nt = 0; nt < 7; ++nt) c1[nt] = MFMA16(aOA, Bw[(SET_W1 + nt) * 64 + lane], zero);
#pragma unroll
        for (int nt = 0; nt < 2; ++nt) {
            f32x4 po = MFMA16(aOA, Bw[(SET_WOBS + nt) * 64 + lane], zero);
            f32x4 pa = MFMA16(aOA, Bw[(SET_WACT + nt) * 64 + lane], zero);
            int col = nt * 16 + r16;
            bool v = col < 20;
            float aO = v ? (bobs[col] + pos[20 + col]) : 0.f;
            float aA = v ? (bact[col] + pos[40 + col]) : 0.f;
#pragma unroll
            for (int j = 0; j < 4; ++j) { po[j] += aO; pa[j] += aA; }
            xf[1][nt][mt] = po;
            xf[2][nt][mt] = pa;
        }
        // pack h1 -> ACT (4 spans of 32 feats; span3 hi-half = zeros)
#pragma unroll
        for (int m = 0; m < 4; ++m) {
            int cA = m * 32 + r16, cBc = m * 32 + 16 + r16;
            float ba = (cA < 100) ? b1[cA] : 0.f;
            float bb = (m < 3 && cBc < 100) ? b1[cBc] : 0.f;
#pragma unroll
            for (int j = 0; j < 4; ++j) {
                float lo = fmaxf(c1[2 * m][j] + ba, 0.f);
                float hi = (m < 3) ? fmaxf(c1[2 * m + 1][j] + bb, 0.f) : 0.f;
                SW[960 + (kb * 4 + j) * 68 + m * 16 + r16] = pk_bf16(lo, hi);
            }
        }
#pragma unroll
        for (int ks = 0; ks < 4; ++ks)
            aH1[mt][ks] = *(const bf16x8*)(S + ACTu + r16 * 136 + ks * 32 + kb * 8);
    }

    // ---- P2: W2 -> relu -> W3 (B-fragments shared across both M-tiles) -----
    f32x4 mo[2][2]; // [mt][nt2]
    mo[0][0] = zero; mo[0][1] = zero; mo[1][0] = zero; mo[1][1] = zero;
#pragma unroll 1
    for (int np = 0; np < 10; ++np) {
        f32x4 cs[2][2]; // [sub][mt]
#pragma unroll
        for (int sub = 0; sub < 2; ++sub) {
            cs[sub][0] = zero; cs[sub][1] = zero;
#pragma unroll
            for (int ks = 0; ks < 4; ++ks) {
                bf16x8 bw = Bw[(SET_W2 + (np * 2 + sub) * 4 + ks) * 64 + lane];
                cs[sub][0] = MFMA16(aH1[0][ks], bw, cs[sub][0]);
                cs[sub][1] = MFMA16(aH1[1][ks], bw, cs[sub][1]);
            }
        }
        int c0 = np * 32 + r16, c1c = np * 32 + 16 + r16;
        float b20 = (c0 < 300) ? b2[c0] : 0.f;
        float b21 = (c1c < 300) ? b2[c1c] : 0.f;
        bf16x8 aH2[2];
#pragma unroll
        for (int mt = 0; mt < 2; ++mt) {
            unsigned* SW = smw + mt * (AR / 2);
#pragma unroll
            for (int j = 0; j < 4; ++j)
                SW[2048 + (kb * 4 + j) * 20 + r16] =
                    pk_bf16(fmaxf(cs[0][mt][j] + b20, 0.f), fmaxf(cs[1][mt][j] + b21, 0.f));
            aH2[mt] = *(const bf16x8*)(sm + mt * AR + H2Tu + r16 * 40 + kb * 8);
        }
#pragma unroll
        for (int nt2 = 0; nt2 < 2; ++nt2) {
            bf16x8 bw3 = Bw[(SET_W3 + nt2 * 10 + np) * 64 + lane];
            mo[0][nt2] = MFMA16(aH2[0], bw3, mo[0][nt2]);
            mo[1][nt2] = MFMA16(aH2[1], bw3, mo[1][nt2]);
        }
    }

    // ---- P3: stack + pos; store x for all tokens ----------------------------
#pragma unroll
    for (int nt = 0; nt < 2; ++nt) {
        int col = nt * 16 + r16;
        float a0 = (col < 20) ? (b3[col] + pos[col]) : 0.f;
#pragma unroll
        for (int mt = 0; mt < 2; ++mt) {
            f32x4 tt = mo[mt][nt];
#pragma unroll
            for (int j = 0; j < 4; ++j) tt[j] += a0;
            xf[0][nt][mt] = tt;
        }
    }
#pragma unroll
    for (int t = 0; t < 3; ++t)
#pragma unroll
        for (int mt = 0; mt < 2; ++mt) {
            unsigned* SW = smw + mt * (AR / 2);
#pragma unroll
            for (int j = 0; j < 4; ++j)
                SW[t * 320 + (kb * 4 + j) * 20 + r16] = pk_bf16(xf[t][0][mt][j], xf[t][1][mt][j]);
        }

    // ---- attention lane-address prep (lane-only, layer-invariant) -----------
    const int ah = lane & 3, ar = lane >> 2;
    const int swA = (ar & 7) << 2;
    int adr_q[5], adr_k[5], adr_v[5];
#pragma unroll
    for (int d = 0; d < 5; ++d) {
        adr_q[d] = qoff(ah * 5 + d, swA);
        adr_k[d] = qoff(20 + ah * 5 + d, swA);
        adr_v[d] = qoff(40 + ah * 5 + d, swA);
    }

    // ---- P4: 3 encoder layers ------------------------------------------------
#pragma unroll 1
    for (int l = 0; l < 3; ++l) {
        // hoisted per-layer biases / LN params
        float bq[4];
#pragma unroll
        for (int nt = 0; nt < 4; ++nt) {
            int col = nt * 16 + r16;
            bq[nt] = (col < 60) ? bqkv[l * 60 + col] : 0.f;
        }
        float bo0 = bo[l * 20 + r16];
        float bo1 = (r16 < 4) ? bo[l * 20 + 16 + r16] : 0.f;
        float fb0 = bf2[l * 20 + r16];
        float fb1 = (r16 < 4) ? bf2[l * 20 + 16 + r16] : 0.f;
        float g1a = g1[l * 20 + r16], e1a = be1[l * 20 + r16];
        float g1b = (r16 < 4) ? g1[l * 20 + 16 + r16] : 0.f;
        float e1b = (r16 < 4) ? be1[l * 20 + 16 + r16] : 0.f;
        float g2a = g2[l * 20 + r16], e2a = be2[l * 20 + r16];
        float g2b = (r16 < 4) ? g2[l * 20 + 16 + r16] : 0.f;
        float e2b = (r16 < 4) ? be2[l * 20 + 16 + r16] : 0.f;

        // -- QKV GEMM (B shared across mt), pack into swizzled QKV tile --
#pragma unroll 1
        for (int t = 0; t < 3; ++t) {
            bf16x8 aX0 = *(const bf16x8*)(sm + 0 * AR + t * 640 + r16 * 40 + kb * 8);
            bf16x8 aX1 = *(const bf16x8*)(sm + 1 * AR + t * 640 + r16 * 40 + kb * 8);
            f32x4 cq[2][4];
#pragma unroll
            for (int nt = 0; nt < 4; ++nt) {
                bf16x8 bw = Bw[(SET_WQKV + l * 4 + nt) * 64 + lane];
                cq[0][nt] = MFMA16(aX0, bw, zero);
                cq[1][nt] = MFMA16(aX1, bw, zero);
            }
#pragma unroll
            for (int mt = 0; mt < 2; ++mt) {
                unsigned* SW = smw + mt * (AR / 2);
#pragma unroll
                for (int j = 0; j < 4; ++j) {
                    int row = kb * 4 + j;
                    int rsw = (row & 7) << 2;
                    SW[960 + t * 512 + row * 32 + (r16 ^ rsw)] =
                        pk_bf16(cq[mt][0][j] + bq[0], cq[mt][1][j] + bq[1]);
                    SW[960 + t * 512 + row * 32 + ((16 + r16) ^ rsw)] =
                        pk_bf16(cq[mt][2][j] + bq[2], cq[mt][3][j] + bq[3]);
                }
            }
        }

        // -- attention: lane = (row ar, head ah); o overwrites q slots --
#pragma unroll
        for (int mt = 0; mt < 2; ++mt) {
            ushort_t* S = sm + mt * AR;
            const int qb = QKVu + ar * 64;
            float q[3][5], kk[3][5], vv[3][5];
#pragma unroll
            for (int s = 0; s < 3; ++s)
#pragma unroll
                for (int d = 0; d < 5; ++d) {
                    q[s][d] = bf2f(S[qb + s * 1024 + adr_q[d]]);
                    kk[s][d] = bf2f(S[qb + s * 1024 + adr_k[d]]);
                    vv[s][d] = bf2f(S[qb + s * 1024 + adr_v[d]]);
                }
            float o[3][5];
#pragma unroll
            for (int s = 0; s < 3; ++s) {
                float sc[3];
#pragma unroll
                for (int t2 = 0; t2 < 3; ++t2) {
                    float a = 0.f;
#pragma unroll
                    for (int d = 0; d < 5; ++d) a = fmaf(q[s][d], kk[t2][d], a);
                    sc[t2] = a * 0.44721359549995793f;
                }
                float m = fmaxf(sc[0], fmaxf(sc[1], sc[2]));
                float e0 = __expf(sc[0] - m), e1 = __expf(sc[1] - m), e2 = __expf(sc[2] - m);
                float inv = 1.f / (e0 + e1 + e2);
                e0 *= inv; e1 *= inv; e2 *= inv;
#pragma unroll
                for (int d = 0; d < 5; ++d)
                    o[s][d] = fmaf(e0, vv[0][d], fmaf(e1, vv[1][d], e2 * vv[2][d]));
            }
#pragma unroll
            for (int s = 0; s < 3; ++s)
#pragma unroll
                for (int d = 0; d < 5; ++d)
                    S[qb + s * 1024 + adr_q[d]] = (ushort_t)pk_bf16(o[s][d], o[s][d]);
        }

        // -- Wo + residual + LN1 for ALL tokens (then QKV region is dead) --
        bf16x8 bw_o0 = Bw[(SET_WO + l * 2 + 0) * 64 + lane];
        bf16x8 bw_o1 = Bw[(SET_WO + l * 2 + 1) * 64 + lane];
#pragma unroll 1
        for (int t = 0; t < 3; ++t) {
            int rsw = (r16 & 7) << 2;
#pragma unroll
            for (int mt = 0; mt < 2; ++mt) {
                const ushort_t* S = sm + mt * AR;
                bf16x8 aO = *(const bf16x8*)(S + QKVu + t * 1024 + r16 * 64 + (((kb * 4) ^ rsw) << 1));
                f32x4 cw0 = MFMA16(aO, bw_o0, zero);
                f32x4 cw1 = MFMA16(aO, bw_o1, zero);
                f32x4 y0 = xf[t][0][mt], y1 = xf[t][1][mt];
#pragma unroll
                for (int j = 0; j < 4; ++j) { y0[j] += cw0[j] + bo0; y1[j] += cw1[j] + bo1; }
                ln20(y0, y1, g1a, e1a, g1b, e1b);
                xf[t][0][mt] = y0; xf[t][1][mt] = y1;
                unsigned* SW = smw + mt * (AR / 2);
#pragma unroll
                for (int j = 0; j < 4; ++j)
                    SW[t * 320 + (kb * 4 + j) * 20 + r16] = pk_bf16(y0[j], y1[j]);
            }
        }

        // -- FFN per token (hidden aliases dead QKV region) --
#pragma unroll 1
        for (int t = 0; t < 3; ++t) {
            bf16x8 aX[2];
#pragma unroll
            for (int mt = 0; mt < 2; ++mt)
                aX[mt] = *(const bf16x8*)(sm + mt * AR + t * 640 + r16 * 40 + kb * 8);
            // FFN1: pack hidden in span pairs
#pragma unroll
            for (int m = 0; m < 4; ++m) {
                bf16x8 bwa = Bw[(SET_WF1 + l * 8 + 2 * m) * 64 + lane];
                bf16x8 bwb = Bw[(SET_WF1 + l * 8 + 2 * m + 1) * 64 + lane];
                float f0 = bf1[l * 128 + m * 32 + r16];
                float f1 = bf1[l * 128 + m * 32 + 16 + r16];
#pragma unroll
                for (int mt = 0; mt < 2; ++mt) {
                    f32x4 ca = MFMA16(aX[mt], bwa, zero);
                    f32x4 cb = MFMA16(aX[mt], bwb, zero);
                    unsigned* SW = smw + mt * (AR / 2);
#pragma unroll
                    for (int j = 0; j < 4; ++j)
                        SW[960 + (kb * 4 + j) * 68 + m * 16 + r16] =
                            pk_bf16(fmaxf(ca[j] + f0, 0.f), fmaxf(cb[j] + f1, 0.f));
                }
            }
            // FFN2
            bf16x8 aF[2][4];
#pragma unroll
            for (int mt = 0; mt < 2; ++mt)
#pragma unroll
                for (int ks = 0; ks < 4; ++ks)
                    aF[mt][ks] = *(const bf16x8*)(sm + mt * AR + ACTu + r16 * 136 + ks * 32 + kb * 8);
            f32x4 c2[2][2];
            c2[0][0] = zero; c2[0][1] = zero; c2[1][0] = zero; c2[1][1] = zero;
#pragma unroll
            for (int g = 0; g < 2; ++g)
#pragma unroll
                for (int ks = 0; ks < 4; ++ks) {
                    bf16x8 bw = Bw[(SET_WF2 + l * 8 + g * 4 + ks) * 64 + lane];
                    c2[0][g] = MFMA16(aF[0][ks], bw, c2[0][g]);
                    c2[1][g] = MFMA16(aF[1][ks], bw, c2[1][g]);
                }
#pragma unroll
            for (int mt = 0; mt < 2; ++mt) {
                f32x4 z0 = xf[t][0][mt], z1 = xf[t][1][mt];
#pragma unroll
                for (int j = 0; j < 4; ++j) { z0[j] += c2[mt][0][j] + fb0; z1[j] += c2[mt][1][j] + fb1; }
                ln20(z0, z1, g2a, e2a, g2b, e2b);
                xf[t][0][mt] = z0; xf[t][1][mt] = z1;
                unsigned* SW = smw + mt * (AR / 2);
#pragma unroll
                for (int j = 0; j < 4; ++j)
                    SW[t * 320 + (kb * 4 + j) * 20 + r16] = pk_bf16(z0[j], z1[j]);
            }
        }
    }

    // ---- P5: head (B,60) @ Wfc^T + bfc --------------------------------------
#pragma unroll
    for (int mt = 0; mt < 2; ++mt) {
        f32x4 p = zero;
#pragma unroll
        for (int t = 0; t < 3; ++t) {
            float w0 = Wfc[t * 20 + r16];
            float w1 = (r16 < 4) ? Wfc[t * 20 + 16 + r16] : 0.f;
#pragma unroll
            for (int j = 0; j < 4; ++j)
                p[j] = fmaf(xf[t][0][mt][j], w0, fmaf(xf[t][1][mt][j], w1, p[j]));
        }
#pragma unroll
        for (int m = 1; m < 16; m <<= 1)
#pragma unroll
            for (int j = 0; j < 4; ++j) p[j] += __shfl_xor(p[j], m);
        if (r16 < 4) {
            float v = (r16 == 0) ? p[0] : (r16 == 1) ? p[1] : (r16 == 2) ? p[2] : p[3];
            out[row0 + mt * 16 + kb * 4 + r16] = v + bfc[0];
        }
    }
}

} // namespace

extern "C" void kernel_launch(void* const* d_in, const int* in_sizes, int n_in,
                              void* d_out, int out_size, void* d_ws, size_t ws_size,
                              hipStream_t stream) {
    (void)in_sizes; (void)n_in; (void)out_size; (void)ws_size;
    const float* obs  = (const float*)d_in[0];
    const float* act  = (const float*)d_in[1];
    const float* W1   = (const float*)d_in[2];
    const float* b1   = (const float*)d_in[3];
    const float* W2   = (const float*)d_in[4];
    const float* b2   = (const float*)d_in[5];
    const float* W3   = (const float*)d_in[6];
    const float* b3   = (const float*)d_in[7];
    const float* Wobs = (const float*)d_in[8];
    const float* bobs = (const float*)d_in[9];
    const float* Wact = (const float*)d_in[10];
    const float* bact = (const float*)d_in[11];
    const float* pos  = (const float*)d_in[12];
    const float* Wqkv = (const float*)d_in[13];
    const float* bqkv = (const float*)d_in[14];
    const float* Wo   = (const float*)d_in[15];
    const float* bo   = (const float*)d_in[16];
    const float* g1   = (const float*)d_in[17];
    const float* be1  = (const float*)d_in[18];
    const float* Wf1  = (const float*)d_in[19];
    const float* bf1  = (const float*)d_in[20];
    const float* Wf2  = (const float*)d_in[21];
    const float* bf2  = (const float*)d_in[22];
    const float* g2   = (const float*)d_in[23];
    const float* be2  = (const float*)d_in[24];
    const float* Wfc  = (const float*)d_in[25];
    const float* bfc  = (const float*)d_in[26];

    ushort_t* wsb = (ushort_t*)d_ws;

    hipLaunchKernelGGL(prep_weights, dim3(NSETS), dim3(64), 0, stream,
                       W1, W2, W3, Wobs, Wact, Wqkv, Wo, Wf1, Wf2, wsb);
    hipLaunchKernelGGL(oat_mfma2, dim3(kB / 32), dim3(64), 0, stream,
                       obs, act, b1, b2, b3, bobs, bact, pos, bqkv, bo,
                       g1, be1, bf1, bf2, g2, be2, Wfc, bfc, wsb, (float*)d_out);
}

// Round 4
// 230.439 us; speedup vs baseline: 3.6667x; 1.2963x over previous
//
#include <hip/hip_runtime.h>

typedef unsigned short ushort_t;
typedef short bf16x8 __attribute__((ext_vector_type(8)));
typedef float f32x4 __attribute__((ext_vector_type(4)));

#define MFMA16(a, b, c) __builtin_amdgcn_mfma_f32_16x16x32_bf16((a), (b), (c), 0, 0, 0)
// sum across the 16-lane row group: xor1, xor2 (quad_perm), then ror4, ror8
#define DPP_ADD(v, ctrl) \
    ((v) + __int_as_float(__builtin_amdgcn_mov_dpp(__float_as_int(v), (ctrl), 0xF, 0xF, true)))

namespace {

constexpr int kB = 262144;

// ws B-fragment set bases (1 set = 64 lanes x 8 bf16 = 1 KiB)
constexpr int SET_W1 = 0;     // (100,23)  NT=7  KS=1
constexpr int SET_W2 = 7;     // (300,100) NT=20 KS=4
constexpr int SET_W3 = 87;    // (20,300)  NT=2  KS=10
constexpr int SET_WOBS = 107; // (20,17)   NT=2  KS=1
constexpr int SET_WACT = 109; // (20,6)    NT=2  KS=1, k shifted +17
constexpr int SET_WQKV = 111; // 3 x (60,20)  NT=4 KS=1
constexpr int SET_WO = 123;   // 3 x (20,20)  NT=2 KS=1
constexpr int SET_WF1 = 129;  // 3 x (128,20) NT=8 KS=1
constexpr int SET_WF2 = 153;  // 3 x (20,128) NT=2 KS=4
constexpr int NSETS = 177;

// per-wave LDS arena (ushort units). Arena = 4992 ushorts (9984 B).
constexpr int AR = 4992;
// XA:  [3 tok][16 rows][pitch 40]  x (pair-permuted bf16); token0 doubles as oa staging
// QKV: [3 tok][16 rows][pitch 64]  qkv, dword-XOR-swizzled; o overwrites in place
// ACT: [16][pitch 136]             h1 / ffn hidden — ALIASES QKV (disjoint in time)
// H2T: [16][pitch 40]              W2->W3 staging (aliases QKV tok2 tail)
constexpr int QKVu = 1920; // ushort base
constexpr int ACTu = 1920;
constexpr int H2Tu = 4096;

__device__ __forceinline__ unsigned pk_bf16(float lo, float hi) {
    unsigned r;
    asm("v_cvt_pk_bf16_f32 %0, %1, %2" : "=v"(r) : "v"(lo), "v"(hi));
    return r;
}
__device__ __forceinline__ float bf2f(ushort_t h) {
    return __uint_as_float(((unsigned)h) << 16);
}
__device__ __forceinline__ float red16(float v) {
    v = DPP_ADD(v, 0xB1);   // quad_perm [1,0,3,2]  (xor 1)
    v = DPP_ADD(v, 0x4E);   // quad_perm [2,3,0,1]  (xor 2)
    v = DPP_ADD(v, 0x124);  // row_ror:4
    v = DPP_ADD(v, 0x128);  // row_ror:8
    return v;
}
// feature f (0..63) -> ushort slot in a pair-permuted 64-wide row (no swizzle)
__device__ __forceinline__ int fslot(int f) {
    return ((f >> 5) << 5) + ((f & 15) << 1) + ((f >> 4) & 1);
}
// swizzled ushort offset within a QKV row; sw = (row&7)<<2
__device__ __forceinline__ int qoff(int f, int sw) {
    int s = fslot(f);
    return (((s >> 1) ^ sw) << 1) | (s & 1);
}

// ---------------- weight prep: fp32 -> bf16 B-fragments (permuted k) --------
__global__ void prep_weights(const float* __restrict__ W1, const float* __restrict__ W2,
                             const float* __restrict__ W3, const float* __restrict__ Wobs,
                             const float* __restrict__ Wact, const float* __restrict__ Wqkv,
                             const float* __restrict__ Wo, const float* __restrict__ Wf1,
                             const float* __restrict__ Wf2, ushort_t* __restrict__ ws) {
    int s = blockIdx.x, lane = threadIdx.x;
    const float* src;
    int Nout, Kin, kshift = 0, nt, ks;
    if (s < SET_W2) { src = W1; Nout = 100; Kin = 23; nt = s; ks = 0; }
    else if (s < SET_W3) { int t = s - SET_W2; src = W2; Nout = 300; Kin = 100; nt = t >> 2; ks = t & 3; }
    else if (s < SET_WOBS) { int t = s - SET_W3; src = W3; Nout = 20; Kin = 300; nt = t / 10; ks = t % 10; }
    else if (s < SET_WACT) { int t = s - SET_WOBS; src = Wobs; Nout = 20; Kin = 17; nt = t; ks = 0; }
    else if (s < SET_WQKV) { int t = s - SET_WACT; src = Wact; Nout = 20; Kin = 6; kshift = 17; nt = t; ks = 0; }
    else if (s < SET_WO) { int t = s - SET_WQKV; src = Wqkv + (t >> 2) * 1200; Nout = 60; Kin = 20; nt = t & 3; ks = 0; }
    else if (s < SET_WF1) { int t = s - SET_WO; src = Wo + (t >> 1) * 400; Nout = 20; Kin = 20; nt = t & 1; ks = 0; }
    else if (s < SET_WF2) { int t = s - SET_WF1; src = Wf1 + (t >> 3) * 2560; Nout = 128; Kin = 20; nt = t & 7; ks = 0; }
    else { int t = s - SET_WF2; src = Wf2 + (t >> 3) * 2560; Nout = 20; Kin = 128; int r = t & 7; nt = r >> 2; ks = r & 3; }

    int n = nt * 16 + (lane & 15);
    ushort_t h[8];
#pragma unroll
    for (int j = 0; j < 8; ++j) {
        int m = (lane >> 4) * 8 + j;             // k-slot within 32-span
        int kw = (m >> 1) + ((m & 1) << 4);      // pair-permuted feature within span
        int k = ks * 32 + kw;
        float v = 0.f;
        if (n < Nout && k >= kshift && k < kshift + Kin) v = src[n * Kin + (k - kshift)];
        unsigned u = __float_as_uint(v);
        h[j] = (ushort_t)((u + 0x7FFFu + ((u >> 16) & 1u)) >> 16);
    }
    uint4 pk;
    pk.x = (unsigned)h[0] | ((unsigned)h[1] << 16);
    pk.y = (unsigned)h[2] | ((unsigned)h[3] << 16);
    pk.z = (unsigned)h[4] | ((unsigned)h[5] << 16);
    pk.w = (unsigned)h[6] | ((unsigned)h[7] << 16);
    ((uint4*)ws)[s * 64 + lane] = pk;
}

// LN over 20 valid cols; y1 cols (16+r16)>=20 are exact zeros; ga1/ba1 pre-masked
__device__ __forceinline__ void ln20(f32x4& y0, f32x4& y1, float ga0, float ba0,
                                     float ga1, float ba1) {
#pragma unroll
    for (int j = 0; j < 4; ++j) {
        float s = red16(y0[j] + y1[j]);
        float s2 = red16(y0[j] * y0[j] + y1[j] * y1[j]);
        float mean = s * 0.05f;
        float var = s2 * 0.05f - mean * mean;
        float r = rsqrtf(var + 1e-5f);
        y0[j] = (y0[j] - mean) * r * ga0 + ba0;
        y1[j] = (y1[j] - mean) * r * ga1 + ba1;
    }
}

__global__ __launch_bounds__(128, 4)
void oat_mfma3(const float* __restrict__ obs, const float* __restrict__ act,
               const float* __restrict__ b1, const float* __restrict__ b2,
               const float* __restrict__ b3, const float* __restrict__ bobs,
               const float* __restrict__ bact, const float* __restrict__ pos,
               const float* __restrict__ bqkv, const float* __restrict__ bo,
               const float* __restrict__ g1, const float* __restrict__ be1,
               const float* __restrict__ bf1, const float* __restrict__ bf2,
               const float* __restrict__ g2, const float* __restrict__ be2,
               const float* __restrict__ Wfc, const float* __restrict__ bfc,
               const ushort_t* __restrict__ wsb, float* __restrict__ out) {
    __shared__ __align__(16) ushort_t sm[2 * AR];
    const int lane = threadIdx.x & 63, wid = threadIdx.x >> 6;
    const int r16 = lane & 15, kb = lane >> 4;
    const int row0 = blockIdx.x * 32 + wid * 16;
    ushort_t* S = sm + wid * AR;
    unsigned* SW = (unsigned*)S;
    const bf16x8* Bw = (const bf16x8*)wsb;
    const f32x4 zero = {0.f, 0.f, 0.f, 0.f};

    // ---- P0: stage oa (32 features: obs 0..16, act 17..22, pad) ------------
#pragma unroll
    for (int it = 0; it < 4; ++it) {
        int idx = it * 64 + lane;
        int r = idx >> 4, d = idx & 15;
        int gr = row0 + r;
        float lo = obs[gr * 17 + d];
        float hi = (d == 0) ? obs[gr * 17 + 16] : ((d <= 6) ? act[gr * 6 + (d - 1)] : 0.f);
        SW[r * 20 + d] = pk_bf16(lo, hi);
    }

    // ---- P1: W1 (h1) + obs/act projections ---------------------------------
    f32x4 xf[3][2]; // [token][nt]
    bf16x8 aOA = *(const bf16x8*)(S + r16 * 40 + kb * 8);
    f32x4 c1[7];
#pragma unroll
    for (int nt = 0; nt < 7; ++nt) c1[nt] = MFMA16(aOA, Bw[(SET_W1 + nt) * 64 + lane], zero);
#pragma unroll
    for (int nt = 0; nt < 2; ++nt) {
        f32x4 po = MFMA16(aOA, Bw[(SET_WOBS + nt) * 64 + lane], zero);
        f32x4 pa = MFMA16(aOA, Bw[(SET_WACT + nt) * 64 + lane], zero);
        int col = nt * 16 + r16;
        bool v = col < 20;
        float aO = v ? (bobs[col] + pos[20 + col]) : 0.f;
        float aA = v ? (bact[col] + pos[40 + col]) : 0.f;
#pragma unroll
        for (int j = 0; j < 4; ++j) { po[j] += aO; pa[j] += aA; }
        xf[1][nt] = po;
        xf[2][nt] = pa;
    }
    // pack h1 -> ACT (4 spans of 32 feats; span3 hi-half = zeros)
#pragma unroll
    for (int m = 0; m < 4; ++m) {
        int cA = m * 32 + r16, cBc = m * 32 + 16 + r16;
        float ba = (cA < 100) ? b1[cA] : 0.f;
        float bb = (m < 3 && cBc < 100) ? b1[cBc] : 0.f;
#pragma unroll
        for (int j = 0; j < 4; ++j) {
            float lo = fmaxf(c1[2 * m][j] + ba, 0.f);
            float hi = (m < 3) ? fmaxf(c1[2 * m + 1][j] + bb, 0.f) : 0.f;
            SW[960 + (kb * 4 + j) * 68 + m * 16 + r16] = pk_bf16(lo, hi);
        }
    }
    bf16x8 aH1[4];
#pragma unroll
    for (int ks = 0; ks < 4; ++ks)
        aH1[ks] = *(const bf16x8*)(S + ACTu + r16 * 136 + ks * 32 + kb * 8);

    // ---- P2: W2 -> relu -> W3 ----------------------------------------------
    f32x4 mo[2];
    mo[0] = zero; mo[1] = zero;
#pragma unroll 1
    for (int np = 0; np < 10; ++np) {
        f32x4 cs[2];
#pragma unroll
        for (int sub = 0; sub < 2; ++sub) {
            cs[sub] = zero;
#pragma unroll
            for (int ks = 0; ks < 4; ++ks)
                cs[sub] = MFMA16(aH1[ks], Bw[(SET_W2 + (np * 2 + sub) * 4 + ks) * 64 + lane], cs[sub]);
        }
        int c0 = np * 32 + r16, c1c = np * 32 + 16 + r16;
        float b20 = (c0 < 300) ? b2[c0] : 0.f;
        float b21 = (c1c < 300) ? b2[c1c] : 0.f;
#pragma unroll
        for (int j = 0; j < 4; ++j)
            SW[2048 + (kb * 4 + j) * 20 + r16] =
                pk_bf16(fmaxf(cs[0][j] + b20, 0.f), fmaxf(cs[1][j] + b21, 0.f));
        bf16x8 aH2 = *(const bf16x8*)(S + H2Tu + r16 * 40 + kb * 8);
#pragma unroll
        for (int nt2 = 0; nt2 < 2; ++nt2)
            mo[nt2] = MFMA16(aH2, Bw[(SET_W3 + nt2 * 10 + np) * 64 + lane], mo[nt2]);
    }

    // ---- P3: stack + pos; store x for all tokens ----------------------------
#pragma unroll
    for (int nt = 0; nt < 2; ++nt) {
        int col = nt * 16 + r16;
        float a0 = (col < 20) ? (b3[col] + pos[col]) : 0.f;
        f32x4 tt = mo[nt];
#pragma unroll
        for (int j = 0; j < 4; ++j) tt[j] += a0;
        xf[0][nt] = tt;
    }
#pragma unroll
    for (int t = 0; t < 3; ++t)
#pragma unroll
        for (int j = 0; j < 4; ++j)
            SW[t * 320 + (kb * 4 + j) * 20 + r16] = pk_bf16(xf[t][0][j], xf[t][1][j]);

    // ---- attention lane-address prep (lane-only, layer-invariant) -----------
    const int ah = lane & 3, ar = lane >> 2;
    const int swA = (ar & 7) << 2;
    int adr_q[5], adr_k[5], adr_v[5];
#pragma unroll
    for (int d = 0; d < 5; ++d) {
        adr_q[d] = qoff(ah * 5 + d, swA);
        adr_k[d] = qoff(20 + ah * 5 + d, swA);
        adr_v[d] = qoff(40 + ah * 5 + d, swA);
    }

    // ---- P4: 3 encoder layers ------------------------------------------------
#pragma unroll 1
    for (int l = 0; l < 3; ++l) {
        // hoisted per-layer biases / LN params
        float bq[4];
#pragma unroll
        for (int nt = 0; nt < 4; ++nt) {
            int col = nt * 16 + r16;
            bq[nt] = (col < 60) ? bqkv[l * 60 + col] : 0.f;
        }
        float bo0 = bo[l * 20 + r16];
        float bo1 = (r16 < 4) ? bo[l * 20 + 16 + r16] : 0.f;
        float fb0 = bf2[l * 20 + r16];
        float fb1 = (r16 < 4) ? bf2[l * 20 + 16 + r16] : 0.f;
        float g1a = g1[l * 20 + r16], e1a = be1[l * 20 + r16];
        float g1b = (r16 < 4) ? g1[l * 20 + 16 + r16] : 0.f;
        float e1b = (r16 < 4) ? be1[l * 20 + 16 + r16] : 0.f;
        float g2a = g2[l * 20 + r16], e2a = be2[l * 20 + r16];
        float g2b = (r16 < 4) ? g2[l * 20 + 16 + r16] : 0.f;
        float e2b = (r16 < 4) ? be2[l * 20 + 16 + r16] : 0.f;

        // -- QKV GEMM (B-frags loaded once, 12 MFMAs in one window) --
        {
            bf16x8 bwq[4];
#pragma unroll
            for (int nt = 0; nt < 4; ++nt) bwq[nt] = Bw[(SET_WQKV + l * 4 + nt) * 64 + lane];
#pragma unroll
            for (int t = 0; t < 3; ++t) {
                bf16x8 aX = *(const bf16x8*)(S + t * 640 + r16 * 40 + kb * 8);
                f32x4 cq[4];
#pragma unroll
                for (int nt = 0; nt < 4; ++nt) cq[nt] = MFMA16(aX, bwq[nt], zero);
#pragma unroll
                for (int j = 0; j < 4; ++j) {
                    int row = kb * 4 + j;
                    int rsw = (row & 7) << 2;
                    SW[960 + t * 512 + row * 32 + (r16 ^ rsw)] =
                        pk_bf16(cq[0][j] + bq[0], cq[1][j] + bq[1]);
                    SW[960 + t * 512 + row * 32 + ((16 + r16) ^ rsw)] =
                        pk_bf16(cq[2][j] + bq[2], cq[3][j] + bq[3]);
                }
            }
        }

        // -- attention: lane = (row ar, head ah); o overwrites q slots --
        {
            const int qb = QKVu + ar * 64;
            float q[3][5], kk[3][5], vv[3][5];
#pragma unroll
            for (int s = 0; s < 3; ++s)
#pragma unroll
                for (int d = 0; d < 5; ++d) {
                    q[s][d] = bf2f(S[qb + s * 1024 + adr_q[d]]);
                    kk[s][d] = bf2f(S[qb + s * 1024 + adr_k[d]]);
                    vv[s][d] = bf2f(S[qb + s * 1024 + adr_v[d]]);
                }
            float o[3][5];
#pragma unroll
            for (int s = 0; s < 3; ++s) {
                float sc[3];
#pragma unroll
                for (int t2 = 0; t2 < 3; ++t2) {
                    float a = 0.f;
#pragma unroll
                    for (int d = 0; d < 5; ++d) a = fmaf(q[s][d], kk[t2][d], a);
                    sc[t2] = a * 0.44721359549995793f;
                }
                float m = fmaxf(sc[0], fmaxf(sc[1], sc[2]));
                float e0 = __expf(sc[0] - m), e1 = __expf(sc[1] - m), e2 = __expf(sc[2] - m);
                float inv = 1.f / (e0 + e1 + e2);
                e0 *= inv; e1 *= inv; e2 *= inv;
#pragma unroll
                for (int d = 0; d < 5; ++d)
                    o[s][d] = fmaf(e0, vv[0][d], fmaf(e1, vv[1][d], e2 * vv[2][d]));
            }
#pragma unroll
            for (int s = 0; s < 3; ++s)
#pragma unroll
                for (int d = 0; d < 5; ++d)
                    S[qb + s * 1024 + adr_q[d]] = (ushort_t)pk_bf16(o[s][d], o[s][d]);
        }

        // -- Wo + residual + LN1 for ALL tokens (then QKV region is dead) --
        {
            bf16x8 bw_o0 = Bw[(SET_WO + l * 2 + 0) * 64 + lane];
            bf16x8 bw_o1 = Bw[(SET_WO + l * 2 + 1) * 64 + lane];
            int rsw = (r16 & 7) << 2;
#pragma unroll
            for (int t = 0; t < 3; ++t) {
                bf16x8 aO = *(const bf16x8*)(S + QKVu + t * 1024 + r16 * 64 + (((kb * 4) ^ rsw) << 1));
                f32x4 cw0 = MFMA16(aO, bw_o0, zero);
                f32x4 cw1 = MFMA16(aO, bw_o1, zero);
                f32x4 y0 = xf[t][0], y1 = xf[t][1];
#pragma unroll
                for (int j = 0; j < 4; ++j) { y0[j] += cw0[j] + bo0; y1[j] += cw1[j] + bo1; }
                ln20(y0, y1, g1a, e1a, g1b, e1b);
                xf[t][0] = y0; xf[t][1] = y1;
#pragma unroll
                for (int j = 0; j < 4; ++j)
                    SW[t * 320 + (kb * 4 + j) * 20 + r16] = pk_bf16(y0[j], y1[j]);
            }
        }

        // -- FFN per token (hidden aliases dead QKV region) --
#pragma unroll 1
        for (int t = 0; t < 3; ++t) {
            bf16x8 aX = *(const bf16x8*)(S + t * 640 + r16 * 40 + kb * 8);
            // FFN1: pack hidden in span pairs
#pragma unroll
            for (int m = 0; m < 4; ++m) {
                bf16x8 bwa = Bw[(SET_WF1 + l * 8 + 2 * m) * 64 + lane];
                bf16x8 bwb = Bw[(SET_WF1 + l * 8 + 2 * m + 1) * 64 + lane];
                float f0 = bf1[l * 128 + m * 32 + r16];
                float f1 = bf1[l * 128 + m * 32 + 16 + r16];
                f32x4 ca = MFMA16(aX, bwa, zero);
                f32x4 cb = MFMA16(aX, bwb, zero);
#pragma unroll
                for (int j = 0; j < 4; ++j)
                    SW[960 + (kb * 4 + j) * 68 + m * 16 + r16] =
                        pk_bf16(fmaxf(ca[j] + f0, 0.f), fmaxf(cb[j] + f1, 0.f));
            }
            // FFN2
            f32x4 c2[2];
            c2[0] = zero; c2[1] = zero;
#pragma unroll
            for (int ks = 0; ks < 4; ++ks) {
                bf16x8 aF = *(const bf16x8*)(S + ACTu + r16 * 136 + ks * 32 + kb * 8);
                c2[0] = MFMA16(aF, Bw[(SET_WF2 + l * 8 + ks) * 64 + lane], c2[0]);
                c2[1] = MFMA16(aF, Bw[(SET_WF2 + l * 8 + 4 + ks) * 64 + lane], c2[1]);
            }
            f32x4 z0 = xf[t][0], z1 = xf[t][1];
#pragma unroll
            for (int j = 0; j < 4; ++j) { z0[j] += c2[0][j] + fb0; z1[j] += c2[1][j] + fb1; }
            ln20(z0, z1, g2a, e2a, g2b, e2b);
            xf[t][0] = z0; xf[t][1] = z1;
#pragma unroll
            for (int j = 0; j < 4; ++j)
                SW[t * 320 + (kb * 4 + j) * 20 + r16] = pk_bf16(z0[j], z1[j]);
        }
    }

    // ---- P5: head (B,60) @ Wfc^T + bfc --------------------------------------
    f32x4 p = zero;
#pragma unroll
    for (int t = 0; t < 3; ++t) {
        float w0 = Wfc[t * 20 + r16];
        float w1 = (r16 < 4) ? Wfc[t * 20 + 16 + r16] : 0.f;
#pragma unroll
        for (int j = 0; j < 4; ++j)
            p[j] = fmaf(xf[t][0][j], w0, fmaf(xf[t][1][j], w1, p[j]));
    }
#pragma unroll
    for (int j = 0; j < 4; ++j) p[j] = red16(p[j]);
    if (r16 < 4) {
        float v = (r16 == 0) ? p[0] : (r16 == 1) ? p[1] : (r16 == 2) ? p[2] : p[3];
        out[row0 + kb * 4 + r16] = v + bfc[0];
    }
}

} // namespace

extern "C" void kernel_launch(void* const* d_in, const int* in_sizes, int n_in,
                              void* d_out, int out_size, void* d_ws, size_t ws_size,
                              hipStream_t stream) {
    (void)in_sizes; (void)n_in; (void)out_size; (void)ws_size;
    const float* obs  = (const float*)d_in[0];
    const float* act  = (const float*)d_in[1];
    const float* W1   = (const float*)d_in[2];
    const float* b1   = (const float*)d_in[3];
    const float* W2   = (const float*)d_in[4];
    const float* b2   = (const float*)d_in[5];
    const float* W3   = (const float*)d_in[6];
    const float* b3   = (const float*)d_in[7];
    const float* Wobs = (const float*)d_in[8];
    const float* bobs = (const float*)d_in[9];
    const float* Wact = (const float*)d_in[10];
    const float* bact = (const float*)d_in[11];
    const float* pos  = (const float*)d_in[12];
    const float* Wqkv = (const float*)d_in[13];
    const float* bqkv = (const float*)d_in[14];
    const float* Wo   = (const float*)d_in[15];
    const float* bo   = (const float*)d_in[16];
    const float* g1   = (const float*)d_in[17];
    const float* be1  = (const float*)d_in[18];
    const float* Wf1  = (const float*)d_in[19];
    const float* bf1  = (const float*)d_in[20];
    const float* Wf2  = (const float*)d_in[21];
    const float* bf2  = (const float*)d_in[22];
    const float* g2   = (const float*)d_in[23];
    const float* be2  = (const float*)d_in[24];
    const float* Wfc  = (const float*)d_in[25];
    const float* bfc  = (const float*)d_in[26];

    ushort_t* wsb = (ushort_t*)d_ws;

    hipLaunchKernelGGL(prep_weights, dim3(NSETS), dim3(64), 0, stream,
                       W1, W2, W3, Wobs, Wact, Wqkv, Wo, Wf1, Wf2, wsb);
    hipLaunchKernelGGL(oat_mfma3, dim3(kB / 32), dim3(128), 0, stream,
                       obs, act, b1, b2, b3, bobs, bact, pos, bqkv, bo,
                       g1, be1, bf1, bf2, g2, be2, Wfc, bfc, wsb, (float*)d_out);
}

// Round 8
// 206.937 us; speedup vs baseline: 4.0831x; 1.1136x over previous
//
#include <hip/hip_runtime.h>

typedef unsigned short ushort_t;
typedef short bf16x8 __attribute__((ext_vector_type(8)));
typedef float f32x4 __attribute__((ext_vector_type(4)));

#define MFMA16(a, b, c) __builtin_amdgcn_mfma_f32_16x16x32_bf16((a), (b), (c), 0, 0, 0)
#define DPP_ADD(v, ctrl) \
    ((v) + __int_as_float(__builtin_amdgcn_mov_dpp(__float_as_int(v), (ctrl), 0xF, 0xF, true)))
// Compiler-only memory barrier: staging writes (unsigned*/ushort*) and fragment
// reads (bf16x8*/uint4*) are type-punned (TBAA no-alias); pin program order at
// phase boundaries. DS pipe is in-order per wave, so no s_waitcnt needed.
#define LDS_FENCE() asm volatile("" ::: "memory")

namespace {

constexpr int kB = 262144;

// ws B-fragment set bases (1 set = 64 lanes x 8 bf16 = 1 KiB)
constexpr int SET_W1 = 0;     // (100,23)  NT=7  KS=1
constexpr int SET_W2 = 7;     // (300,100) NT=20 KS=4
constexpr int SET_W3 = 87;    // (20,300)  NT=2  KS=10
constexpr int SET_WOBS = 107; // (20,17)   NT=2  KS=1
constexpr int SET_WACT = 109; // (20,6)    NT=2  KS=1, k shifted +17
constexpr int SET_WQKV = 111; // 3 x (60,20)  NT=4 KS=1
constexpr int SET_WO = 123;   // 3 x (20,20)  NT=2 KS=1
constexpr int SET_WF1 = 129;  // 3 x (128,20) NT=8 KS=1
constexpr int SET_WF2 = 153;  // 3 x (20,128) NT=2 KS=4
constexpr int NSETS = 177;

// per-wave LDS arena (ushort units). Arena = 4992 ushorts (9984 B).
constexpr int AR = 4992;
// XA:  [3 tok][16 rows][pitch 40]  x (pair-permuted bf16); token0 doubles as oa staging
// QKV: [3 tok][16 rows][pitch 64]  qkv, dword-XOR-swizzled; o overwrites in place
// ACT: [16][pitch 136]             h1 / ffn hidden — ALIASES QKV (disjoint in time)
// H2T: [16][pitch 40]              W2->W3 staging (aliases QKV tok2 tail)
constexpr int QKVu = 1920; // ushort base
constexpr int ACTu = 1920;
constexpr int H2Tu = 4096;

__device__ __forceinline__ unsigned pk_bf16(float lo, float hi) {
    unsigned r;
    asm("v_cvt_pk_bf16_f32 %0, %1, %2" : "=v"(r) : "v"(lo), "v"(hi));
    return r;
}
__device__ __forceinline__ float bf2f(ushort_t h) {
    return __uint_as_float(((unsigned)h) << 16);
}
__device__ __forceinline__ float red16(float v) {
    v = DPP_ADD(v, 0xB1);   // quad_perm [1,0,3,2]  (xor 1)
    v = DPP_ADD(v, 0x4E);   // quad_perm [2,3,0,1]  (xor 2)
    v = DPP_ADD(v, 0x124);  // row_ror:4
    v = DPP_ADD(v, 0x128);  // row_ror:8
    return v;
}
// feature f (0..63) -> ushort slot in a pair-permuted 64-wide row (no swizzle)
__device__ __forceinline__ int fslot(int f) {
    return ((f >> 5) << 5) + ((f & 15) << 1) + ((f >> 4) & 1);
}
// swizzled ushort offset within a QKV row; sw = (row&7)<<2
__device__ __forceinline__ int qoff(int f, int sw) {
    int s = fslot(f);
    return (((s >> 1) ^ sw) << 1) | (s & 1);
}

// ---------------- weight prep: fp32 -> bf16 B-fragments (permuted k) --------
__global__ void prep_weights(const float* __restrict__ W1, const float* __restrict__ W2,
                             const float* __restrict__ W3, const float* __restrict__ Wobs,
                             const float* __restrict__ Wact, const float* __restrict__ Wqkv,
                             const float* __restrict__ Wo, const float* __restrict__ Wf1,
                             const float* __restrict__ Wf2, ushort_t* __restrict__ ws) {
    int s = blockIdx.x, lane = threadIdx.x;
    const float* src;
    int Nout, Kin, kshift = 0, nt, ks;
    if (s < SET_W2) { src = W1; Nout = 100; Kin = 23; nt = s; ks = 0; }
    else if (s < SET_W3) { int t = s - SET_W2; src = W2; Nout = 300; Kin = 100; nt = t >> 2; ks = t & 3; }
    else if (s < SET_WOBS) { int t = s - SET_W3; src = W3; Nout = 20; Kin = 300; nt = t / 10; ks = t % 10; }
    else if (s < SET_WACT) { int t = s - SET_WOBS; src = Wobs; Nout = 20; Kin = 17; nt = t; ks = 0; }
    else if (s < SET_WQKV) { int t = s - SET_WACT; src = Wact; Nout = 20; Kin = 6; kshift = 17; nt = t; ks = 0; }
    else if (s < SET_WO) { int t = s - SET_WQKV; src = Wqkv + (t >> 2) * 1200; Nout = 60; Kin = 20; nt = t & 3; ks = 0; }
    else if (s < SET_WF1) { int t = s - SET_WO; src = Wo + (t >> 1) * 400; Nout = 20; Kin = 20; nt = t & 1; ks = 0; }
    else if (s < SET_WF2) { int t = s - SET_WF1; src = Wf1 + (t >> 3) * 2560; Nout = 128; Kin = 20; nt = t & 7; ks = 0; }
    else { int t = s - SET_WF2; src = Wf2 + (t >> 3) * 2560; Nout = 20; Kin = 128; int r = t & 7; nt = r >> 2; ks = r & 3; }

    int n = nt * 16 + (lane & 15);
    ushort_t h[8];
#pragma unroll
    for (int j = 0; j < 8; ++j) {
        int m = (lane >> 4) * 8 + j;             // k-slot within 32-span
        int kw = (m >> 1) + ((m & 1) << 4);      // pair-permuted feature within span
        int k = ks * 32 + kw;
        float v = 0.f;
        if (n < Nout && k >= kshift && k < kshift + Kin) v = src[n * Kin + (k - kshift)];
        unsigned u = __float_as_uint(v);
        h[j] = (ushort_t)((u + 0x7FFFu + ((u >> 16) & 1u)) >> 16);
    }
    uint4 pk;
    pk.x = (unsigned)h[0] | ((unsigned)h[1] << 16);
    pk.y = (unsigned)h[2] | ((unsigned)h[3] << 16);
    pk.z = (unsigned)h[4] | ((unsigned)h[5] << 16);
    pk.w = (unsigned)h[6] | ((unsigned)h[7] << 16);
    ((uint4*)ws)[s * 64 + lane] = pk;
}

// LN over 20 valid cols; y1 cols (16+r16)>=20 are exact zeros; ga1/ba1 pre-masked
__device__ __forceinline__ void ln20(f32x4& y0, f32x4& y1, float ga0, float ba0,
                                     float ga1, float ba1) {
#pragma unroll
    for (int j = 0; j < 4; ++j) {
        float s = red16(y0[j] + y1[j]);
        float s2 = red16(y0[j] * y0[j] + y1[j] * y1[j]);
        float mean = s * 0.05f;
        float var = s2 * 0.05f - mean * mean;
        float r = rsqrtf(var + 1e-5f);
        y0[j] = (y0[j] - mean) * r * ga0 + ba0;
        y1[j] = (y1[j] - mean) * r * ga1 + ba1;
    }
}

__global__ __launch_bounds__(128, 4)
void oat_mfma7(const float* __restrict__ obs, const float* __restrict__ act,
               const float* __restrict__ b1, const float* __restrict__ b2,
               const float* __restrict__ b3, const float* __restrict__ bobs,
               const float* __restrict__ bact, const float* __restrict__ pos,
               const float* __restrict__ bqkv, const float* __restrict__ bo,
               const float* __restrict__ g1, const float* __restrict__ be1,
               const float* __restrict__ bf1, const float* __restrict__ bf2,
               const float* __restrict__ g2, const float* __restrict__ be2,
               const float* __restrict__ Wfc, const float* __restrict__ bfc,
               const ushort_t* __restrict__ wsb, float* __restrict__ out) {
    __shared__ __align__(16) ushort_t sm[2 * AR];
    const int lane = threadIdx.x & 63, wid = threadIdx.x >> 6;
    const int r16 = lane & 15, kb = lane >> 4;
    const int row0 = blockIdx.x * 32 + wid * 16;
    ushort_t* S = sm + wid * AR;
    unsigned* SW = (unsigned*)S;
    const bf16x8* Bw = (const bf16x8*)wsb;
    const f32x4 zero = {0.f, 0.f, 0.f, 0.f};

    // ---- P0: stage oa (32 features: obs 0..16, act 17..22, pad) ------------
#pragma unroll
    for (int it = 0; it < 4; ++it) {
        int idx = it * 64 + lane;
        int r = idx >> 4, d = idx & 15;
        int gr = row0 + r;
        float lo = obs[gr * 17 + d];
        float hi = (d == 0) ? obs[gr * 17 + 16] : ((d <= 6) ? act[gr * 6 + (d - 1)] : 0.f);
        SW[r * 20 + d] = pk_bf16(lo, hi);
    }
    LDS_FENCE();  // oa stores -> aOA read

    // ---- P1: W1 (h1) + obs/act projections ---------------------------------
    f32x4 xf[3][2]; // [token][nt]
    bf16x8 aOA = *(const bf16x8*)(S + r16 * 40 + kb * 8);
    f32x4 c1[7];
#pragma unroll
    for (int nt = 0; nt < 7; ++nt) c1[nt] = MFMA16(aOA, Bw[(SET_W1 + nt) * 64 + lane], zero);
#pragma unroll
    for (int nt = 0; nt < 2; ++nt) {
        f32x4 po = MFMA16(aOA, Bw[(SET_WOBS + nt) * 64 + lane], zero);
        f32x4 pa = MFMA16(aOA, Bw[(SET_WACT + nt) * 64 + lane], zero);
        int col = nt * 16 + r16;
        bool v = col < 20;
        float aO = v ? (bobs[col] + pos[20 + col]) : 0.f;
        float aA = v ? (bact[col] + pos[40 + col]) : 0.f;
#pragma unroll
        for (int j = 0; j < 4; ++j) { po[j] += aO; pa[j] += aA; }
        xf[1][nt] = po;
        xf[2][nt] = pa;
    }
    // pack h1 -> ACT (4 spans of 32 feats; span3 hi-half = zeros)
#pragma unroll
    for (int m = 0; m < 4; ++m) {
        int cA = m * 32 + r16, cBc = m * 32 + 16 + r16;
        float ba = (cA < 100) ? b1[cA] : 0.f;
        float bb = (m < 3 && cBc < 100) ? b1[cBc] : 0.f;
#pragma unroll
        for (int j = 0; j < 4; ++j) {
            float lo = fmaxf(c1[2 * m][j] + ba, 0.f);
            float hi = (m < 3) ? fmaxf(c1[2 * m + 1][j] + bb, 0.f) : 0.f;
            SW[960 + (kb * 4 + j) * 68 + m * 16 + r16] = pk_bf16(lo, hi);
        }
    }
    LDS_FENCE();  // ACT stores -> aH1 reads
    bf16x8 aH1[4];
#pragma unroll
    for (int ks = 0; ks < 4; ++ks)
        aH1[ks] = *(const bf16x8*)(S + ACTu + r16 * 136 + ks * 32 + kb * 8);

    // ---- P2: W2 -> relu -> W3 ----------------------------------------------
    f32x4 mo[2];
    mo[0] = zero; mo[1] = zero;
#pragma unroll 1
    for (int np = 0; np < 10; ++np) {
        f32x4 cs[2];
#pragma unroll
        for (int sub = 0; sub < 2; ++sub) {
            cs[sub] = zero;
#pragma unroll
            for (int ks = 0; ks < 4; ++ks)
                cs[sub] = MFMA16(aH1[ks], Bw[(SET_W2 + (np * 2 + sub) * 4 + ks) * 64 + lane], cs[sub]);
        }
        int c0 = np * 32 + r16, c1c = np * 32 + 16 + r16;
        float b20 = (c0 < 300) ? b2[c0] : 0.f;
        float b21 = (c1c < 300) ? b2[c1c] : 0.f;
        LDS_FENCE();  // prev iter's aH2 read (buffer reuse, WAR) -> these stores
#pragma unroll
        for (int j = 0; j < 4; ++j)
            SW[2048 + (kb * 4 + j) * 20 + r16] =
                pk_bf16(fmaxf(cs[0][j] + b20, 0.f), fmaxf(cs[1][j] + b21, 0.f));
        LDS_FENCE();  // H2T stores -> aH2 read
        bf16x8 aH2 = *(const bf16x8*)(S + H2Tu + r16 * 40 + kb * 8);
#pragma unroll
        for (int nt2 = 0; nt2 < 2; ++nt2)
            mo[nt2] = MFMA16(aH2, Bw[(SET_W3 + nt2 * 10 + np) * 64 + lane], mo[nt2]);
    }

    // ---- P3: stack + pos; store x for all tokens ----------------------------
#pragma unroll
    for (int nt = 0; nt < 2; ++nt) {
        int col = nt * 16 + r16;
        float a0 = (col < 20) ? (b3[col] + pos[col]) : 0.f;
        f32x4 tt = mo[nt];
#pragma unroll
        for (int j = 0; j < 4; ++j) tt[j] += a0;
        xf[0][nt] = tt;
    }
#pragma unroll
    for (int t = 0; t < 3; ++t)
#pragma unroll
        for (int j = 0; j < 4; ++j)
            SW[t * 320 + (kb * 4 + j) * 20 + r16] = pk_bf16(xf[t][0][j], xf[t][1][j]);

    // ---- attention lane-address prep (lane-only, layer-invariant) -----------
    const int ah = lane & 3, ar = lane >> 2;
    const int swA = (ar & 7) << 2;
    int adr_q[5], adr_k[5], adr_v[5];
#pragma unroll
    for (int d = 0; d < 5; ++d) {
        adr_q[d] = qoff(ah * 5 + d, swA);
        adr_k[d] = qoff(20 + ah * 5 + d, swA);
        adr_v[d] = qoff(40 + ah * 5 + d, swA);
    }

    // ---- P4: 3 encoder layers ------------------------------------------------
#pragma unroll 1
    for (int l = 0; l < 3; ++l) {
        // hoisted per-layer biases / LN params
        float bq[4];
#pragma unroll
        for (int nt = 0; nt < 4; ++nt) {
            int col = nt * 16 + r16;
            bq[nt] = (col < 60) ? bqkv[l * 60 + col] : 0.f;
        }
        float bo0 = bo[l * 20 + r16];
        float bo1 = (r16 < 4) ? bo[l * 20 + 16 + r16] : 0.f;
        float fb0 = bf2[l * 20 + r16];
        float fb1 = (r16 < 4) ? bf2[l * 20 + 16 + r16] : 0.f;
        float g1a = g1[l * 20 + r16], e1a = be1[l * 20 + r16];
        float g1b = (r16 < 4) ? g1[l * 20 + 16 + r16] : 0.f;
        float e1b = (r16 < 4) ? be1[l * 20 + 16 + r16] : 0.f;
        float g2a = g2[l * 20 + r16], e2a = be2[l * 20 + r16];
        float g2b = (r16 < 4) ? g2[l * 20 + 16 + r16] : 0.f;
        float e2b = (r16 < 4) ? be2[l * 20 + 16 + r16] : 0.f;

        LDS_FENCE();  // x stores (P3 / prev-layer FFN) -> aX reads; ACT WAR
        // -- QKV GEMM (B-frags loaded once, 12 MFMAs in one window) --
        {
            bf16x8 bwq[4];
#pragma unroll
            for (int nt = 0; nt < 4; ++nt) bwq[nt] = Bw[(SET_WQKV + l * 4 + nt) * 64 + lane];
#pragma unroll
            for (int t = 0; t < 3; ++t) {
                bf16x8 aX = *(const bf16x8*)(S + t * 640 + r16 * 40 + kb * 8);
                f32x4 cq[4];
#pragma unroll
                for (int nt = 0; nt < 4; ++nt) cq[nt] = MFMA16(aX, bwq[nt], zero);
#pragma unroll
                for (int j = 0; j < 4; ++j) {
                    int row = kb * 4 + j;
                    int rsw = (row & 7) << 2;
                    SW[960 + t * 512 + row * 32 + (r16 ^ rsw)] =
                        pk_bf16(cq[0][j] + bq[0], cq[1][j] + bq[1]);
                    SW[960 + t * 512 + row * 32 + ((16 + r16) ^ rsw)] =
                        pk_bf16(cq[2][j] + bq[2], cq[3][j] + bq[3]);
                }
            }
        }
        LDS_FENCE();  // QKV pack stores -> attention ushort reads

        // -- attention: lane = (row ar, head ah); o overwrites q slots --
        {
            const int qb = QKVu + ar * 64;
            float q[3][5], kk[3][5], vv[3][5];
#pragma unroll
            for (int s = 0; s < 3; ++s)
#pragma unroll
                for (int d = 0; d < 5; ++d) {
                    q[s][d] = bf2f(S[qb + s * 1024 + adr_q[d]]);
                    kk[s][d] = bf2f(S[qb + s * 1024 + adr_k[d]]);
                    vv[s][d] = bf2f(S[qb + s * 1024 + adr_v[d]]);
                }
            float o[3][5];
#pragma unroll
            for (int s = 0; s < 3; ++s) {
                float sc[3];
#pragma unroll
                for (int t2 = 0; t2 < 3; ++t2) {
                    float a = 0.f;
#pragma unroll
                    for (int d = 0; d < 5; ++d) a = fmaf(q[s][d], kk[t2][d], a);
                    sc[t2] = a * 0.44721359549995793f;
                }
                float m = fmaxf(sc[0], fmaxf(sc[1], sc[2]));
                float e0 = __expf(sc[0] - m), e1 = __expf(sc[1] - m), e2 = __expf(sc[2] - m);
                float inv = 1.f / (e0 + e1 + e2);
                e0 *= inv; e1 *= inv; e2 *= inv;
#pragma unroll
                for (int d = 0; d < 5; ++d)
                    o[s][d] = fmaf(e0, vv[0][d], fmaf(e1, vv[1][d], e2 * vv[2][d]));
            }
#pragma unroll
            for (int s = 0; s < 3; ++s)
#pragma unroll
                for (int d = 0; d < 5; ++d)
                    S[qb + s * 1024 + adr_q[d]] = (ushort_t)pk_bf16(o[s][d], o[s][d]);
        }
        LDS_FENCE();  // o stores -> aO reads

        // -- Wo + residual + LN1 for ALL tokens (then QKV region is dead) --
        {
            bf16x8 bw_o0 = Bw[(SET_WO + l * 2 + 0) * 64 + lane];
            bf16x8 bw_o1 = Bw[(SET_WO + l * 2 + 1) * 64 + lane];
            int rsw = (r16 & 7) << 2;
#pragma unroll
            for (int t = 0; t < 3; ++t) {
                bf16x8 aO = *(const bf16x8*)(S + QKVu + t * 1024 + r16 * 64 + (((kb * 4) ^ rsw) << 1));
                f32x4 cw0 = MFMA16(aO, bw_o0, zero);
                f32x4 cw1 = MFMA16(aO, bw_o1, zero);
                f32x4 y0 = xf[t][0], y1 = xf[t][1];
#pragma unroll
                for (int j = 0; j < 4; ++j) { y0[j] += cw0[j] + bo0; y1[j] += cw1[j] + bo1; }
                ln20(y0, y1, g1a, e1a, g1b, e1b);
                xf[t][0] = y0; xf[t][1] = y1;
#pragma unroll
                for (int j = 0; j < 4; ++j)
                    SW[t * 320 + (kb * 4 + j) * 20 + r16] = pk_bf16(y0[j], y1[j]);
            }
        }

        // -- FFN all tokens (hidden aliases dead QKV region), fully unrolled --
#pragma unroll
        for (int t = 0; t < 3; ++t) {
            LDS_FENCE();  // x stores -> aX read; prev-t aF reads (ACT WAR) -> stores
            bf16x8 aX = *(const bf16x8*)(S + t * 640 + r16 * 40 + kb * 8);
            // FFN1: pack hidden in span pairs
#pragma unroll
            for (int m = 0; m < 4; ++m) {
                bf16x8 bwa = Bw[(SET_WF1 + l * 8 + 2 * m) * 64 + lane];
                bf16x8 bwb = Bw[(SET_WF1 + l * 8 + 2 * m + 1) * 64 + lane];
                float f0 = bf1[l * 128 + m * 32 + r16];
                float f1 = bf1[l * 128 + m * 32 + 16 + r16];
                f32x4 ca = MFMA16(aX, bwa, zero);
                f32x4 cb = MFMA16(aX, bwb, zero);
#pragma unroll
                for (int j = 0; j < 4; ++j)
                    SW[960 + (kb * 4 + j) * 68 + m * 16 + r16] =
                        pk_bf16(fmaxf(ca[j] + f0, 0.f), fmaxf(cb[j] + f1, 0.f));
            }
            LDS_FENCE();  // ACT stores -> aF reads
            // FFN2
            f32x4 c2[2];
            c2[0] = zero; c2[1] = zero;
#pragma unroll
            for (int ks = 0; ks < 4; ++ks) {
                bf16x8 aF = *(const bf16x8*)(S + ACTu + r16 * 136 + ks * 32 + kb * 8);
                c2[0] = MFMA16(aF, Bw[(SET_WF2 + l * 8 + ks) * 64 + lane], c2[0]);
                c2[1] = MFMA16(aF, Bw[(SET_WF2 + l * 8 + 4 + ks) * 64 + lane], c2[1]);
            }
            f32x4 z0 = xf[t][0], z1 = xf[t][1];
#pragma unroll
            for (int j = 0; j < 4; ++j) { z0[j] += c2[0][j] + fb0; z1[j] += c2[1][j] + fb1; }
            ln20(z0, z1, g2a, e2a, g2b, e2b);
            xf[t][0] = z0; xf[t][1] = z1;
#pragma unroll
            for (int j = 0; j < 4; ++j)
                SW[t * 320 + (kb * 4 + j) * 20 + r16] = pk_bf16(z0[j], z1[j]);
        }
    }

    // ---- P5: head (B,60) @ Wfc^T + bfc --------------------------------------
    f32x4 p = zero;
#pragma unroll
    for (int t = 0; t < 3; ++t) {
        float w0 = Wfc[t * 20 + r16];
        float w1 = (r16 < 4) ? Wfc[t * 20 + 16 + r16] : 0.f;
#pragma unroll
        for (int j = 0; j < 4; ++j)
            p[j] = fmaf(xf[t][0][j], w0, fmaf(xf[t][1][j], w1, p[j]));
    }
#pragma unroll
    for (int j = 0; j < 4; ++j) p[j] = red16(p[j]);
    if (r16 < 4) {
        float v = (r16 == 0) ? p[0] : (r16 == 1) ? p[1] : (r16 == 2) ? p[2] : p[3];
        out[row0 + kb * 4 + r16] = v + bfc[0];
    }
}

} // namespace

extern "C" void kernel_launch(void* const* d_in, const int* in_sizes, int n_in,
                              void* d_out, int out_size, void* d_ws, size_t ws_size,
                              hipStream_t stream) {
    (void)in_sizes; (void)n_in; (void)out_size; (void)ws_size;
    const float* obs  = (const float*)d_in[0];
    const float* act  = (const float*)d_in[1];
    const float* W1   = (const float*)d_in[2];
    const float* b1   = (const float*)d_in[3];
    const float* W2   = (const float*)d_in[4];
    const float* b2   = (const float*)d_in[5];
    const float* W3   = (const float*)d_in[6];
    const float* b3   = (const float*)d_in[7];
    const float* Wobs = (const float*)d_in[8];
    const float* bobs = (const float*)d_in[9];
    const float* Wact = (const float*)d_in[10];
    const float* bact = (const float*)d_in[11];
    const float* pos  = (const float*)d_in[12];
    const float* Wqkv = (const float*)d_in[13];
    const float* bqkv = (const float*)d_in[14];
    const float* Wo   = (const float*)d_in[15];
    const float* bo   = (const float*)d_in[16];
    const float* g1   = (const float*)d_in[17];
    const float* be1  = (const float*)d_in[18];
    const float* Wf1  = (const float*)d_in[19];
    const float* bf1  = (const float*)d_in[20];
    const float* Wf2  = (const float*)d_in[21];
    const float* bf2  = (const float*)d_in[22];
    const float* g2   = (const float*)d_in[23];
    const float* be2  = (const float*)d_in[24];
    const float* Wfc  = (const float*)d_in[25];
    const float* bfc  = (const float*)d_in[26];

    ushort_t* wsb = (ushort_t*)d_ws;

    hipLaunchKernelGGL(prep_weights, dim3(NSETS), dim3(64), 0, stream,
                       W1, W2, W3, Wobs, Wact, Wqkv, Wo, Wf1, Wf2, wsb);
    hipLaunchKernelGGL(oat_mfma7, dim3(kB / 32), dim3(128), 0, stream,
                       obs, act, b1, b2, b3, bobs, bact, pos, bqkv, bo,
                       g1, be1, bf1, bf2, g2, be2, Wfc, bfc, wsb, (float*)d_out);
}